// Round 12
// baseline (413.877 us; speedup 1.0000x reference)
//
#include <hip/hip_runtime.h>

constexpr float EPS = 1e-5f;

#define NPB_LOG 9
#define NPB 512

typedef __attribute__((ext_vector_type(8))) __bf16 bf16x8;
typedef __attribute__((ext_vector_type(4))) float f32x4;
typedef __attribute__((ext_vector_type(2))) float f32x2;

// ---------- bf16 helpers ----------
__device__ __forceinline__ float blo(unsigned u) { return __uint_as_float(u << 16); }
__device__ __forceinline__ float bhi(unsigned u) { return __uint_as_float(u & 0xffff0000u); }
__device__ __forceinline__ unsigned bf1(float f) {
    unsigned u = __float_as_uint(f);
    return (u + 0x7fffu + ((u >> 16) & 1u)) >> 16;
}
__device__ __forceinline__ unsigned pack2(float a, float b) { return bf1(a) | (bf1(b) << 16); }

// ---------- fp8 helpers ----------
__device__ __forceinline__ f32x2 fp8lo(unsigned w) {
    return __builtin_amdgcn_cvt_pk_f32_fp8(w, false);
}
__device__ __forceinline__ f32x2 fp8hi(unsigned w) {
    return __builtin_amdgcn_cvt_pk_f32_fp8(w, true);
}

// accumulate 16 fp8 (one uint4) into s[B..B+15]
template <int B>
__device__ __forceinline__ void acc16(float (&s)[32], uint4 w) {
    f32x2 p;
    p = fp8lo(w.x); s[B + 0] += p[0];  s[B + 1] += p[1];
    p = fp8hi(w.x); s[B + 2] += p[0];  s[B + 3] += p[1];
    p = fp8lo(w.y); s[B + 4] += p[0];  s[B + 5] += p[1];
    p = fp8hi(w.y); s[B + 6] += p[0];  s[B + 7] += p[1];
    p = fp8lo(w.z); s[B + 8] += p[0];  s[B + 9] += p[1];
    p = fp8hi(w.z); s[B + 10] += p[0]; s[B + 11] += p[1];
    p = fp8lo(w.w); s[B + 12] += p[0]; s[B + 13] += p[1];
    p = fp8hi(w.w); s[B + 14] += p[0]; s[B + 15] += p[1];
}

// ---------------- CSR build (locality-aware, uint4-vectorized edge reads) ----------------

__global__ void bucket_hist_kernel(const int* __restrict__ dst, int* __restrict__ bcnt,
                                   int E, int B) {
    __shared__ int h[256];
    int t = threadIdx.x;
    h[t] = 0;
    __syncthreads();
    int E4 = E >> 2;
    const uint4* d4 = reinterpret_cast<const uint4*>(dst);
    for (int i = blockIdx.x * blockDim.x + t; i < E4; i += gridDim.x * blockDim.x) {
        uint4 d = d4[i];
        atomicAdd(&h[d.x >> NPB_LOG], 1);
        atomicAdd(&h[d.y >> NPB_LOG], 1);
        atomicAdd(&h[d.z >> NPB_LOG], 1);
        atomicAdd(&h[d.w >> NPB_LOG], 1);
    }
    if (blockIdx.x == 0 && t < (E & 3))
        atomicAdd(&h[dst[E4 * 4 + t] >> NPB_LOG], 1);
    __syncthreads();
    if (t < B && h[t]) atomicAdd(&bcnt[t], h[t]);
}

__global__ void bucket_scan_kernel(const int* __restrict__ bcnt, int* __restrict__ bstart,
                                   int* __restrict__ cursorB, int B, int E) {
    __shared__ int tmp[256];
    int t = threadIdx.x;
    int v = (t < B) ? bcnt[t] : 0;
    tmp[t] = v;
    __syncthreads();
    for (int off = 1; off < 256; off <<= 1) {
        int x = tmp[t];
        if (t >= off) x += tmp[t - off];
        __syncthreads();
        tmp[t] = x;
        __syncthreads();
    }
    if (t < B) {
        int ex = tmp[t] - v;
        bstart[t] = ex;
        cursorB[t] = ex;
    }
    if (t == 0) bstart[B] = E;
}

__global__ __launch_bounds__(256) void partition_kernel(
    const int* __restrict__ src, const int* __restrict__ dst,
    int* __restrict__ cursorB, unsigned* __restrict__ ebuf, int E, int B) {
    __shared__ int hist[256];
    __shared__ int base[256];
    int t = threadIdx.x;
    hist[t] = 0;
    __syncthreads();
    int e0 = blockIdx.x * 4096;
    int e1 = min(e0 + 4096, E);
    const uint4* d4 = reinterpret_cast<const uint4*>(dst);
    const uint4* s4 = reinterpret_cast<const uint4*>(src);
    int n4 = (e1 - e0) >> 2;
    int i0 = e0 >> 2;
    for (int i = t; i < n4; i += 256) {
        uint4 d = d4[i0 + i];
        atomicAdd(&hist[d.x >> NPB_LOG], 1);
        atomicAdd(&hist[d.y >> NPB_LOG], 1);
        atomicAdd(&hist[d.z >> NPB_LOG], 1);
        atomicAdd(&hist[d.w >> NPB_LOG], 1);
    }
    for (int e = e0 + n4 * 4 + t; e < e1; e += 256)
        atomicAdd(&hist[dst[e] >> NPB_LOG], 1);
    __syncthreads();
    int h = hist[t];
    if (t < B && h) base[t] = atomicAdd(&cursorB[t], h);
    __syncthreads();
    hist[t] = 0;
    __syncthreads();
    for (int i = t; i < n4; i += 256) {
        uint4 d = d4[i0 + i];
        uint4 s = s4[i0 + i];
        int b0i = d.x >> NPB_LOG, b1i = d.y >> NPB_LOG, b2i = d.z >> NPB_LOG, b3i = d.w >> NPB_LOG;
        int o0 = atomicAdd(&hist[b0i], 1);
        ebuf[base[b0i] + o0] = (s.x << NPB_LOG) | (d.x & (NPB - 1));
        int o1 = atomicAdd(&hist[b1i], 1);
        ebuf[base[b1i] + o1] = (s.y << NPB_LOG) | (d.y & (NPB - 1));
        int o2 = atomicAdd(&hist[b2i], 1);
        ebuf[base[b2i] + o2] = (s.z << NPB_LOG) | (d.z & (NPB - 1));
        int o3 = atomicAdd(&hist[b3i], 1);
        ebuf[base[b3i] + o3] = (s.w << NPB_LOG) | (d.w & (NPB - 1));
    }
    for (int e = e0 + n4 * 4 + t; e < e1; e += 256) {
        int d = dst[e];
        int b = d >> NPB_LOG;
        int off = atomicAdd(&hist[b], 1);
        ebuf[base[b] + off] = ((unsigned)src[e] << NPB_LOG) | (unsigned)(d & (NPB - 1));
    }
}

__global__ __launch_bounds__(256) void build_csr_kernel(
    const unsigned* __restrict__ ebuf, const int* __restrict__ bstart,
    int* __restrict__ rowptr, float* __restrict__ degInv, int* __restrict__ csr,
    int N, int B) {
    __shared__ int cnt[NPB];
    __shared__ int cur[NPB];
    __shared__ int ps[256];
    int b = blockIdx.x;
    int t = threadIdx.x;
    int nbase = b << NPB_LOG;
    int nn = min(NPB, N - nbase);
    cnt[t] = 0;
    cnt[t + 256] = 0;
    __syncthreads();
    int ebeg = bstart[b], eend = bstart[b + 1];
    int eh = min((4 - (ebeg & 3)) & 3, eend - ebeg) + ebeg;
    for (int e = ebeg + t; e < eh; e += 256)
        atomicAdd(&cnt[ebuf[e] & (NPB - 1)], 1);
    int n4 = (eend - eh) >> 2;
    const uint4* p4 = reinterpret_cast<const uint4*>(ebuf + eh);
    for (int i = t; i < n4; i += 256) {
        uint4 p = p4[i];
        atomicAdd(&cnt[p.x & (NPB - 1)], 1);
        atomicAdd(&cnt[p.y & (NPB - 1)], 1);
        atomicAdd(&cnt[p.z & (NPB - 1)], 1);
        atomicAdd(&cnt[p.w & (NPB - 1)], 1);
    }
    for (int e = eh + n4 * 4 + t; e < eend; e += 256)
        atomicAdd(&cnt[ebuf[e] & (NPB - 1)], 1);
    __syncthreads();
    int c0 = cnt[2 * t], c1 = cnt[2 * t + 1];
    int pair = c0 + c1;
    ps[t] = pair;
    __syncthreads();
    for (int off = 1; off < 256; off <<= 1) {
        int x = ps[t];
        if (t >= off) x += ps[t - off];
        __syncthreads();
        ps[t] = x;
        __syncthreads();
    }
    int exPair = ps[t] - pair;
    int g0 = ebeg + exPair;
    int g1 = g0 + c0;
    cur[2 * t] = g0;
    cur[2 * t + 1] = g1;
    if (2 * t < nn) {
        rowptr[nbase + 2 * t] = g0;
        degInv[nbase + 2 * t] = 1.0f / (float)max(c0, 1);
    }
    if (2 * t + 1 < nn) {
        rowptr[nbase + 2 * t + 1] = g1;
        degInv[nbase + 2 * t + 1] = 1.0f / (float)max(c1, 1);
    }
    if (b == B - 1 && t == 0) rowptr[N] = eend;
    __syncthreads();
    for (int e = ebeg + t; e < eh; e += 256) {
        unsigned p = ebuf[e];
        int pos = atomicAdd(&cur[p & (NPB - 1)], 1);
        csr[pos] = (int)(p >> NPB_LOG);
    }
    for (int i = t; i < n4; i += 256) {
        uint4 p = p4[i];
        int pos;
        pos = atomicAdd(&cur[p.x & (NPB - 1)], 1); csr[pos] = (int)(p.x >> NPB_LOG);
        pos = atomicAdd(&cur[p.y & (NPB - 1)], 1); csr[pos] = (int)(p.y >> NPB_LOG);
        pos = atomicAdd(&cur[p.z & (NPB - 1)], 1); csr[pos] = (int)(p.z >> NPB_LOG);
        pos = atomicAdd(&cur[p.w & (NPB - 1)], 1); csr[pos] = (int)(p.w >> NPB_LOG);
    }
    for (int e = eh + n4 * 4 + t; e < eend; e += 256) {
        unsigned p = ebuf[e];
        int pos = atomicAdd(&cur[p & (NPB - 1)], 1);
        csr[pos] = (int)(p >> NPB_LOG);
    }
}

// ---------------- fused prep: weight swizzles + BN folds, one launch ----------------
__device__ __forceinline__ void swz_one(const float* __restrict__ Wl, const float* __restrict__ Wr,
                                        unsigned short* __restrict__ out, int CL, int CR, int id) {
    int C = CL + CR;
    int CT = C >> 4;
    int lane = id & 63;
    int ctkt = id >> 6;
    int ct = ctkt % CT;
    int kt = ctkt / CT;
    int col = ct * 16 + (lane & 15);
    int k0 = kt * 32 + (lane >> 4) * 8;
#pragma unroll
    for (int i = 0; i < 8; ++i) {
        int k = k0 + i;
        float w = (col < CL) ? Wl[(size_t)k * CL + col] : Wr[(size_t)k * CR + (col - CL)];
        out[(size_t)id * 8 + i] = (unsigned short)bf1(w);
    }
}

__global__ void prep_kernel(const float* __restrict__ Wl0, const float* __restrict__ Wr0,
                            const float* __restrict__ Wl1, const float* __restrict__ Wr1,
                            const float* __restrict__ Wl2, const float* __restrict__ Wr2,
                            const float* __restrict__ g0, const float* __restrict__ b0,
                            const float* __restrict__ m0, const float* __restrict__ v0,
                            const float* __restrict__ g1, const float* __restrict__ b1,
                            const float* __restrict__ m1, const float* __restrict__ v1,
                            unsigned short* __restrict__ Wsw0, unsigned short* __restrict__ Wsw1,
                            unsigned short* __restrict__ Wsw2,
                            float* __restrict__ bnA0, float* __restrict__ bnB0,
                            float* __restrict__ bnA1, float* __restrict__ bnB1) {
    int bid = blockIdx.x;
    int t = threadIdx.x;
    if (bid < 16) {
        swz_one(Wl0, Wr0, Wsw0, 128, 128, bid * 256 + t);
    } else if (bid < 32) {
        swz_one(Wl1, Wr1, Wsw1, 128, 128, (bid - 16) * 256 + t);
    } else if (bid < 40) {
        swz_one(Wl2, Wr2, Wsw2, 64, 64, (bid - 32) * 256 + t);
    } else {
        if (t < 128) {
            float A = g0[t] * rsqrtf(v0[t] + EPS);
            bnA0[t] = A;
            bnB0[t] = b0[t] - m0[t] * A;
        } else {
            int c = t - 128;
            float A = g1[c] * rsqrtf(v1[c] + EPS);
            bnA1[c] = A;
            bnB1[c] = b1[c] - m1[c] * A;
        }
    }
}

// ---------------- layer 0 GEMM (operand-swapped, LDS-staged f32 A): [tL|tR] = x @ [Wl|Wr] ----------------
__global__ __launch_bounds__(256, 4) void gemm0_kernel(
    const float* __restrict__ Af, const unsigned short* __restrict__ Wsw,
    const float* __restrict__ bl,
    unsigned char* __restrict__ tL, unsigned short* __restrict__ tR, int n) {
    constexpr int CT = 8;
    __shared__ unsigned short As[64][136];

    int tid = threadIdx.x;
    int lane = tid & 63;
    int wave = tid >> 6;
    int wr = wave >> 1, wc = wave & 1;
    int blk0 = blockIdx.x * 64;
    int rlo = lane & 15, kq = lane >> 4;

    {
        int srow = tid >> 2;
        int schunk = tid & 3;
        int grow = blk0 + srow;
        uint4 w0 = make_uint4(0, 0, 0, 0), w1 = w0, w2 = w0, w3 = w0;
        if (grow < n) {
            const float4* p = reinterpret_cast<const float4*>(Af + (size_t)grow * 128 + schunk * 32);
            float4 f0 = p[0], f1 = p[1], f2 = p[2], f3 = p[3];
            float4 f4 = p[4], f5 = p[5], f6 = p[6], f7 = p[7];
            w0 = make_uint4(pack2(f0.x, f0.y), pack2(f0.z, f0.w), pack2(f1.x, f1.y), pack2(f1.z, f1.w));
            w1 = make_uint4(pack2(f2.x, f2.y), pack2(f2.z, f2.w), pack2(f3.x, f3.y), pack2(f3.z, f3.w));
            w2 = make_uint4(pack2(f4.x, f4.y), pack2(f4.z, f4.w), pack2(f5.x, f5.y), pack2(f5.z, f5.w));
            w3 = make_uint4(pack2(f6.x, f6.y), pack2(f6.z, f6.w), pack2(f7.x, f7.y), pack2(f7.z, f7.w));
        }
        uint4* d = reinterpret_cast<uint4*>(&As[srow][schunk * 32]);
        d[0] = w0; d[1] = w1; d[2] = w2; d[3] = w3;
    }
    __syncthreads();

    f32x4 acc[2][CT];
#pragma unroll
    for (int nt = 0; nt < 2; ++nt)
#pragma unroll
        for (int c = 0; c < CT; ++c)
#pragma unroll
            for (int k = 0; k < 4; ++k) acc[nt][c][k] = 0.f;

    int lr0 = wr * 32 + rlo;
    int lr1 = wr * 32 + 16 + rlo;

    for (int kt = 0; kt < 4; ++kt) {
        int kb = kt * 32 + kq * 8;
        bf16x8 a0 = *reinterpret_cast<const bf16x8*>(&As[lr0][kb]);
        bf16x8 a1 = *reinterpret_cast<const bf16x8*>(&As[lr1][kb]);
#pragma unroll
        for (int c = 0; c < CT; ++c) {
            int ct_g = wc * CT + c;
            bf16x8 w = *reinterpret_cast<const bf16x8*>(Wsw + ((size_t)(kt * 2 * CT + ct_g) * 64 + lane) * 8);
            acc[0][c] = __builtin_amdgcn_mfma_f32_16x16x32_bf16(w, a0, acc[0][c], 0, 0, 0);
            acc[1][c] = __builtin_amdgcn_mfma_f32_16x16x32_bf16(w, a1, acc[1][c], 0, 0, 0);
        }
    }

#pragma unroll
    for (int nt = 0; nt < 2; ++nt) {
        int r = blk0 + wr * 32 + nt * 16 + rlo;
        if (r >= n) continue;
#pragma unroll
        for (int c = 0; c < CT; ++c) {
            int colbase = c * 16 + kq * 4;
            if (wc == 0) {
                unsigned w = __builtin_amdgcn_cvt_pk_fp8_f32(acc[nt][c][0], acc[nt][c][1], 0, false);
                w = __builtin_amdgcn_cvt_pk_fp8_f32(acc[nt][c][2], acc[nt][c][3], w, true);
                *reinterpret_cast<unsigned*>(tL + (size_t)r * 128 + colbase) = w;
            } else {
                float4 bv = *reinterpret_cast<const float4*>(bl + colbase);
                uint2 o;
                o.x = pack2(acc[nt][c][0] + bv.x, acc[nt][c][1] + bv.y);
                o.y = pack2(acc[nt][c][2] + bv.z, acc[nt][c][3] + bv.w);
                *reinterpret_cast<uint2*>(tR + (size_t)r * 128 + colbase) = o;
            }
        }
    }
}

// ---------------- fused aggregate->GEMM: h = ReLU(BN(agg(tLin)+tRin)) (LDS only), [tLout|tRout] = h @ W ----------------
// Phase A: 4 lanes/node x 32B; x4-unrolled gathers (8x 16B loads in flight).
// Phase B: operand-swapped MFMA identical to gemm0.
template <int CHALF>
__global__ __launch_bounds__(256, 4) void fusedAG_kernel(
    const unsigned char* __restrict__ tLin, const unsigned short* __restrict__ tRin,
    const float* __restrict__ bnA, const float* __restrict__ bnB,
    const int* __restrict__ rowptr, const int* __restrict__ csr,
    const float* __restrict__ degInv,
    const unsigned short* __restrict__ Wsw, const float* __restrict__ bl,
    unsigned char* __restrict__ tLout, unsigned short* __restrict__ tRout, int n) {
    constexpr int CT = CHALF / 16;
    __shared__ unsigned short As[64][136];

    int tid = threadIdx.x;
    int blk0 = blockIdx.x * 64;

    // ---- phase A: gather + BN + ReLU -> LDS h-tile ----
    {
        int lrow = tid >> 2;
        int t = tid & 3;
        int v = blk0 + lrow;
        uint4* dst = reinterpret_cast<uint4*>(&As[lrow][t * 32]);
        if (v < n) {
            float s[32];
#pragma unroll
            for (int j = 0; j < 32; ++j) s[j] = 0.f;
            int beg = rowptr[v], end = rowptr[v + 1];
            const uint4* T4 = reinterpret_cast<const uint4*>(tLin);
            int e = beg;
            for (; e + 4 <= end; e += 4) {
                const uint4* r0 = T4 + (size_t)csr[e + 0] * 8 + t * 2;
                const uint4* r1 = T4 + (size_t)csr[e + 1] * 8 + t * 2;
                const uint4* r2 = T4 + (size_t)csr[e + 2] * 8 + t * 2;
                const uint4* r3 = T4 + (size_t)csr[e + 3] * 8 + t * 2;
                uint4 a0 = r0[0], a1 = r0[1];
                uint4 b0 = r1[0], b1 = r1[1];
                uint4 c0 = r2[0], c1 = r2[1];
                uint4 d0 = r3[0], d1 = r3[1];
                acc16<0>(s, a0); acc16<16>(s, a1);
                acc16<0>(s, b0); acc16<16>(s, b1);
                acc16<0>(s, c0); acc16<16>(s, c1);
                acc16<0>(s, d0); acc16<16>(s, d1);
            }
            for (; e < end; ++e) {
                const uint4* r0 = T4 + (size_t)csr[e] * 8 + t * 2;
                uint4 a0 = r0[0], a1 = r0[1];
                acc16<0>(s, a0); acc16<16>(s, a1);
            }
            float di = degInv[v];
            const uint4* R4 = reinterpret_cast<const uint4*>(tRin + (size_t)v * 128 + t * 32);
            uint4 rr[4] = { R4[0], R4[1], R4[2], R4[3] };
            const float4* A4 = reinterpret_cast<const float4*>(bnA + t * 32);
            const float4* B4 = reinterpret_cast<const float4*>(bnB + t * 32);
#pragma unroll
            for (int j = 0; j < 4; ++j) {
                uint4 rj = rr[j];
                float4 Aa = A4[2 * j], Ab = A4[2 * j + 1];
                float4 Ba = B4[2 * j], Bb = B4[2 * j + 1];
                float h0 = fmaxf(Aa.x * (s[8 * j + 0] * di + blo(rj.x)) + Ba.x, 0.f);
                float h1 = fmaxf(Aa.y * (s[8 * j + 1] * di + bhi(rj.x)) + Ba.y, 0.f);
                float h2 = fmaxf(Aa.z * (s[8 * j + 2] * di + blo(rj.y)) + Ba.z, 0.f);
                float h3 = fmaxf(Aa.w * (s[8 * j + 3] * di + bhi(rj.y)) + Ba.w, 0.f);
                float h4 = fmaxf(Ab.x * (s[8 * j + 4] * di + blo(rj.z)) + Bb.x, 0.f);
                float h5 = fmaxf(Ab.y * (s[8 * j + 5] * di + bhi(rj.z)) + Bb.y, 0.f);
                float h6 = fmaxf(Ab.z * (s[8 * j + 6] * di + blo(rj.w)) + Bb.z, 0.f);
                float h7 = fmaxf(Ab.w * (s[8 * j + 7] * di + bhi(rj.w)) + Bb.w, 0.f);
                uint4 o;
                o.x = pack2(h0, h1);
                o.y = pack2(h2, h3);
                o.z = pack2(h4, h5);
                o.w = pack2(h6, h7);
                dst[j] = o;
            }
        } else {
            uint4 z = make_uint4(0, 0, 0, 0);
            dst[0] = z; dst[1] = z; dst[2] = z; dst[3] = z;
        }
    }
    __syncthreads();

    // ---- phase B: MFMA ----
    int lane = tid & 63;
    int wave = tid >> 6;
    int wr = wave >> 1, wc = wave & 1;
    int rlo = lane & 15, kq = lane >> 4;

    f32x4 acc[2][CT];
#pragma unroll
    for (int nt = 0; nt < 2; ++nt)
#pragma unroll
        for (int c = 0; c < CT; ++c)
#pragma unroll
            for (int k = 0; k < 4; ++k) acc[nt][c][k] = 0.f;

    int lr0 = wr * 32 + rlo;
    int lr1 = wr * 32 + 16 + rlo;

    for (int kt = 0; kt < 4; ++kt) {
        int kb = kt * 32 + kq * 8;
        bf16x8 a0 = *reinterpret_cast<const bf16x8*>(&As[lr0][kb]);
        bf16x8 a1 = *reinterpret_cast<const bf16x8*>(&As[lr1][kb]);
#pragma unroll
        for (int c = 0; c < CT; ++c) {
            int ct_g = wc * CT + c;
            bf16x8 w = *reinterpret_cast<const bf16x8*>(Wsw + ((size_t)(kt * 2 * CT + ct_g) * 64 + lane) * 8);
            acc[0][c] = __builtin_amdgcn_mfma_f32_16x16x32_bf16(w, a0, acc[0][c], 0, 0, 0);
            acc[1][c] = __builtin_amdgcn_mfma_f32_16x16x32_bf16(w, a1, acc[1][c], 0, 0, 0);
        }
    }

#pragma unroll
    for (int nt = 0; nt < 2; ++nt) {
        int r = blk0 + wr * 32 + nt * 16 + rlo;
        if (r >= n) continue;
#pragma unroll
        for (int c = 0; c < CT; ++c) {
            int colbase = c * 16 + kq * 4;
            if (wc == 0) {
                unsigned w = __builtin_amdgcn_cvt_pk_fp8_f32(acc[nt][c][0], acc[nt][c][1], 0, false);
                w = __builtin_amdgcn_cvt_pk_fp8_f32(acc[nt][c][2], acc[nt][c][3], w, true);
                *reinterpret_cast<unsigned*>(tLout + (size_t)r * CHALF + colbase) = w;
            } else {
                float4 bv = *reinterpret_cast<const float4*>(bl + colbase);
                uint2 o;
                o.x = pack2(acc[nt][c][0] + bv.x, acc[nt][c][1] + bv.y);
                o.y = pack2(acc[nt][c][2] + bv.z, acc[nt][c][3] + bv.w);
                *reinterpret_cast<uint2*>(tRout + (size_t)r * CHALF + colbase) = o;
            }
        }
    }
}

// ---------------- final: out = log_softmax( mean-agg(tL2 fp8) + tR2 bf16 ) ----------------
__global__ void agg64_lsm_kernel(const unsigned char* __restrict__ tL2,
                                 const unsigned short* __restrict__ tR2,
                                 const int* __restrict__ rowptr, const int* __restrict__ csr,
                                 const float* __restrict__ degInv,
                                 float* __restrict__ out, int n) {
    int idx = blockIdx.x * blockDim.x + threadIdx.x;
    int v = idx >> 3;
    int t = idx & 7;
    if (v >= n) return;
    int beg = rowptr[v], end = rowptr[v + 1];
    const uint2* T2 = reinterpret_cast<const uint2*>(tL2);
    float s0 = 0.f, s1 = 0.f, s2 = 0.f, s3 = 0.f, s4 = 0.f, s5 = 0.f, s6 = 0.f, s7 = 0.f;
    int e = beg;
    for (; e + 8 <= end; e += 8) {
        uint2 w0 = T2[(size_t)csr[e + 0] * 8 + t];
        uint2 w1 = T2[(size_t)csr[e + 1] * 8 + t];
        uint2 w2 = T2[(size_t)csr[e + 2] * 8 + t];
        uint2 w3 = T2[(size_t)csr[e + 3] * 8 + t];
        uint2 w4 = T2[(size_t)csr[e + 4] * 8 + t];
        uint2 w5 = T2[(size_t)csr[e + 5] * 8 + t];
        uint2 w6 = T2[(size_t)csr[e + 6] * 8 + t];
        uint2 w7 = T2[(size_t)csr[e + 7] * 8 + t];
        f32x2 p;
        p = fp8lo(w0.x); s0 += p[0]; s1 += p[1];
        p = fp8hi(w0.x); s2 += p[0]; s3 += p[1];
        p = fp8lo(w0.y); s4 += p[0]; s5 += p[1];
        p = fp8hi(w0.y); s6 += p[0]; s7 += p[1];
        p = fp8lo(w1.x); s0 += p[0]; s1 += p[1];
        p = fp8hi(w1.x); s2 += p[0]; s3 += p[1];
        p = fp8lo(w1.y); s4 += p[0]; s5 += p[1];
        p = fp8hi(w1.y); s6 += p[0]; s7 += p[1];
        p = fp8lo(w2.x); s0 += p[0]; s1 += p[1];
        p = fp8hi(w2.x); s2 += p[0]; s3 += p[1];
        p = fp8lo(w2.y); s4 += p[0]; s5 += p[1];
        p = fp8hi(w2.y); s6 += p[0]; s7 += p[1];
        p = fp8lo(w3.x); s0 += p[0]; s1 += p[1];
        p = fp8hi(w3.x); s2 += p[0]; s3 += p[1];
        p = fp8lo(w3.y); s4 += p[0]; s5 += p[1];
        p = fp8hi(w3.y); s6 += p[0]; s7 += p[1];
        p = fp8lo(w4.x); s0 += p[0]; s1 += p[1];
        p = fp8hi(w4.x); s2 += p[0]; s3 += p[1];
        p = fp8lo(w4.y); s4 += p[0]; s5 += p[1];
        p = fp8hi(w4.y); s6 += p[0]; s7 += p[1];
        p = fp8lo(w5.x); s0 += p[0]; s1 += p[1];
        p = fp8hi(w5.x); s2 += p[0]; s3 += p[1];
        p = fp8lo(w5.y); s4 += p[0]; s5 += p[1];
        p = fp8hi(w5.y); s6 += p[0]; s7 += p[1];
        p = fp8lo(w6.x); s0 += p[0]; s1 += p[1];
        p = fp8hi(w6.x); s2 += p[0]; s3 += p[1];
        p = fp8lo(w6.y); s4 += p[0]; s5 += p[1];
        p = fp8hi(w6.y); s6 += p[0]; s7 += p[1];
        p = fp8lo(w7.x); s0 += p[0]; s1 += p[1];
        p = fp8hi(w7.x); s2 += p[0]; s3 += p[1];
        p = fp8lo(w7.y); s4 += p[0]; s5 += p[1];
        p = fp8hi(w7.y); s6 += p[0]; s7 += p[1];
    }
    for (; e < end; ++e) {
        uint2 w = T2[(size_t)csr[e] * 8 + t];
        f32x2 p;
        p = fp8lo(w.x); s0 += p[0]; s1 += p[1];
        p = fp8hi(w.x); s2 += p[0]; s3 += p[1];
        p = fp8lo(w.y); s4 += p[0]; s5 += p[1];
        p = fp8hi(w.y); s6 += p[0]; s7 += p[1];
    }
    float di = degInv[v];
    uint4 rw = reinterpret_cast<const uint4*>(tR2)[(size_t)v * 8 + t];
    float y0 = s0 * di + blo(rw.x);
    float y1 = s1 * di + bhi(rw.x);
    float y2 = s2 * di + blo(rw.y);
    float y3 = s3 * di + bhi(rw.y);
    float y4 = s4 * di + blo(rw.z);
    float y5 = s5 * di + bhi(rw.z);
    float y6 = s6 * di + blo(rw.w);
    float y7 = s7 * di + bhi(rw.w);

    float mx = fmaxf(fmaxf(fmaxf(y0, y1), fmaxf(y2, y3)),
                     fmaxf(fmaxf(y4, y5), fmaxf(y6, y7)));
#pragma unroll
    for (int o = 1; o < 8; o <<= 1) mx = fmaxf(mx, __shfl_xor(mx, o));
    float s = __expf(y0 - mx) + __expf(y1 - mx) + __expf(y2 - mx) + __expf(y3 - mx)
            + __expf(y4 - mx) + __expf(y5 - mx) + __expf(y6 - mx) + __expf(y7 - mx);
#pragma unroll
    for (int o = 1; o < 8; o <<= 1) s += __shfl_xor(s, o);
    float lse = mx + __logf(s);

    float4 oA, oB;
    oA.x = y0 - lse; oA.y = y1 - lse; oA.z = y2 - lse; oA.w = y3 - lse;
    oB.x = y4 - lse; oB.y = y5 - lse; oB.z = y6 - lse; oB.w = y7 - lse;
    float4* O4 = reinterpret_cast<float4*>(out + (size_t)v * 64 + t * 8);
    O4[0] = oA;
    O4[1] = oB;
}

// ---------------- launch ----------------

extern "C" void kernel_launch(void* const* d_in, const int* in_sizes, int n_in,
                              void* d_out, int out_size, void* d_ws, size_t ws_size,
                              hipStream_t stream) {
    const float* x   = (const float*)d_in[0];
    const int*   ei  = (const int*)d_in[1];
    const float* Wl0 = (const float*)d_in[2];
    const float* bl0 = (const float*)d_in[3];
    const float* Wr0 = (const float*)d_in[4];
    const float* g0  = (const float*)d_in[5];
    const float* b0  = (const float*)d_in[6];
    const float* m0  = (const float*)d_in[7];
    const float* v0  = (const float*)d_in[8];
    const float* Wl1 = (const float*)d_in[9];
    const float* bl1 = (const float*)d_in[10];
    const float* Wr1 = (const float*)d_in[11];
    const float* g1  = (const float*)d_in[12];
    const float* b1  = (const float*)d_in[13];
    const float* m1  = (const float*)d_in[14];
    const float* v1  = (const float*)d_in[15];
    const float* Wl2 = (const float*)d_in[16];
    const float* bl2 = (const float*)d_in[17];
    const float* Wr2 = (const float*)d_in[18];
    float* out = (float*)d_out;

    const int N = in_sizes[0] / 128;
    const int E = in_sizes[1] / 2;
    const int B = (N + NPB - 1) >> NPB_LOG;
    const int* src = ei;
    const int* dst = ei + E;

    char* ws = (char*)d_ws;
    size_t off = 0;
    auto alloc = [&](size_t bytes) -> void* {
        void* p = ws + off;
        off += (bytes + 255) & ~(size_t)255;
        return p;
    };
    int*   bcnt    = (int*)alloc(256 * 4);
    int*   bstart  = (int*)alloc(257 * 4);
    int*   cursorB = (int*)alloc(256 * 4);
    int*   rowptr  = (int*)alloc((size_t)(N + 1) * 4);
    float* degInv  = (float*)alloc((size_t)N * 4);
    int*   csr     = (int*)alloc((size_t)E * 4);
    unsigned* ebuf = (unsigned*)alloc((size_t)E * 4);
    unsigned char*  tLa = (unsigned char*)alloc((size_t)N * 128);        // fp8  [N][128] layer0
    unsigned short* tRa = (unsigned short*)alloc((size_t)N * 128 * 2);   // bf16 [N][128] layer0
    unsigned char*  tLb = (unsigned char*)alloc((size_t)N * 128);        // fp8  [N][128] layer1
    unsigned short* tRb = (unsigned short*)alloc((size_t)N * 128 * 2);   // bf16 [N][128] layer1
    unsigned short* Wsw0 = (unsigned short*)alloc(4 * 16 * 64 * 8 * 2);
    unsigned short* Wsw1 = (unsigned short*)alloc(4 * 16 * 64 * 8 * 2);
    unsigned short* Wsw2 = (unsigned short*)alloc(4 * 8 * 64 * 8 * 2);
    float* bnA0 = (float*)alloc(128 * 4);
    float* bnB0 = (float*)alloc(128 * 4);
    float* bnA1 = (float*)alloc(128 * 4);
    float* bnB1 = (float*)alloc(128 * 4);
    unsigned char*  tL2 = tLa;                           // fp8  [N][64] overlays tLa
    unsigned short* tR2 = tRa;                           // bf16 [N][64] overlays tRa

    hipMemsetAsync(bcnt, 0, 256 * 4, stream);

    // CSR build + prep
    bucket_hist_kernel<<<512, 256, 0, stream>>>(dst, bcnt, E, B);
    bucket_scan_kernel<<<1, 256, 0, stream>>>(bcnt, bstart, cursorB, B, E);
    partition_kernel<<<(E + 4095) / 4096, 256, 0, stream>>>(src, dst, cursorB, ebuf, E, B);
    build_csr_kernel<<<B, 256, 0, stream>>>(ebuf, bstart, rowptr, degInv, csr, N, B);
    prep_kernel<<<41, 256, 0, stream>>>(Wl0, Wr0, Wl1, Wr1, Wl2, Wr2,
                                        g0, b0, m0, v0, g1, b1, m1, v1,
                                        Wsw0, Wsw1, Wsw2, bnA0, bnB0, bnA1, bnB1);

    int gemmGrid = (N + 63) / 64;
    int lsmGrid = (int)(((size_t)N * 8 + 255) / 256);

    // layer 0: [tLa|tRa] = x @ [Wl0|Wr0]  (tLa fp8, tRa bf16 with +bl0)
    gemm0_kernel<<<gemmGrid, 256, 0, stream>>>(x, Wsw0, bl0, tLa, tRa, N);
    // layer 1 fused: h0 = ReLU(BN0(agg(tLa)+tRa)) in LDS; [tLb|tRb] = h0 @ [Wl1|Wr1]
    fusedAG_kernel<128><<<gemmGrid, 256, 0, stream>>>(
        tLa, tRa, bnA0, bnB0, rowptr, csr, degInv, Wsw1, bl1, tLb, tRb, N);
    // layer 2 fused: h1 = ReLU(BN1(agg(tLb)+tRb)) in LDS; [tL2|tR2] = h1 @ [Wl2|Wr2]
    fusedAG_kernel<64><<<gemmGrid, 256, 0, stream>>>(
        tLb, tRb, bnA1, bnB1, rowptr, csr, degInv, Wsw2, bl2, tL2, tR2, N);
    // final: out = log_softmax(agg(tL2) + tR2)
    agg64_lsm_kernel<<<lsmGrid, 256, 0, stream>>>(tL2, tR2, rowptr, csr, degInv, out, N);
}

// Round 13
// 342.030 us; speedup vs baseline: 1.2101x; 1.2101x over previous
//
#include <hip/hip_runtime.h>

constexpr float EPS = 1e-5f;

#define NPB_LOG 9
#define NPB 512

typedef __attribute__((ext_vector_type(8))) __bf16 bf16x8;
typedef __attribute__((ext_vector_type(4))) float f32x4;
typedef __attribute__((ext_vector_type(2))) float f32x2;

// ---------- bf16 helpers ----------
__device__ __forceinline__ float blo(unsigned u) { return __uint_as_float(u << 16); }
__device__ __forceinline__ float bhi(unsigned u) { return __uint_as_float(u & 0xffff0000u); }
__device__ __forceinline__ unsigned bf1(float f) {
    unsigned u = __float_as_uint(f);
    return (u + 0x7fffu + ((u >> 16) & 1u)) >> 16;
}
__device__ __forceinline__ unsigned pack2(float a, float b) { return bf1(a) | (bf1(b) << 16); }

// ---------- fp8 helpers ----------
__device__ __forceinline__ f32x2 fp8lo(unsigned w) {
    return __builtin_amdgcn_cvt_pk_f32_fp8(w, false);
}
__device__ __forceinline__ f32x2 fp8hi(unsigned w) {
    return __builtin_amdgcn_cvt_pk_f32_fp8(w, true);
}

// ---------------- CSR build (locality-aware, uint4-vectorized edge reads) ----------------

__global__ void bucket_hist_kernel(const int* __restrict__ dst, int* __restrict__ bcnt,
                                   int E, int B) {
    __shared__ int h[256];
    int t = threadIdx.x;
    h[t] = 0;
    __syncthreads();
    int E4 = E >> 2;
    const uint4* d4 = reinterpret_cast<const uint4*>(dst);
    for (int i = blockIdx.x * blockDim.x + t; i < E4; i += gridDim.x * blockDim.x) {
        uint4 d = d4[i];
        atomicAdd(&h[d.x >> NPB_LOG], 1);
        atomicAdd(&h[d.y >> NPB_LOG], 1);
        atomicAdd(&h[d.z >> NPB_LOG], 1);
        atomicAdd(&h[d.w >> NPB_LOG], 1);
    }
    if (blockIdx.x == 0 && t < (E & 3))
        atomicAdd(&h[dst[E4 * 4 + t] >> NPB_LOG], 1);
    __syncthreads();
    if (t < B && h[t]) atomicAdd(&bcnt[t], h[t]);
}

__global__ void bucket_scan_kernel(const int* __restrict__ bcnt, int* __restrict__ bstart,
                                   int* __restrict__ cursorB, int B, int E) {
    __shared__ int tmp[256];
    int t = threadIdx.x;
    int v = (t < B) ? bcnt[t] : 0;
    tmp[t] = v;
    __syncthreads();
    for (int off = 1; off < 256; off <<= 1) {
        int x = tmp[t];
        if (t >= off) x += tmp[t - off];
        __syncthreads();
        tmp[t] = x;
        __syncthreads();
    }
    if (t < B) {
        int ex = tmp[t] - v;
        bstart[t] = ex;
        cursorB[t] = ex;
    }
    if (t == 0) bstart[B] = E;
}

__global__ __launch_bounds__(256) void partition_kernel(
    const int* __restrict__ src, const int* __restrict__ dst,
    int* __restrict__ cursorB, unsigned* __restrict__ ebuf, int E, int B) {
    __shared__ int hist[256];
    __shared__ int base[256];
    int t = threadIdx.x;
    hist[t] = 0;
    __syncthreads();
    int e0 = blockIdx.x * 4096;
    int e1 = min(e0 + 4096, E);
    const uint4* d4 = reinterpret_cast<const uint4*>(dst);
    const uint4* s4 = reinterpret_cast<const uint4*>(src);
    int n4 = (e1 - e0) >> 2;
    int i0 = e0 >> 2;
    for (int i = t; i < n4; i += 256) {
        uint4 d = d4[i0 + i];
        atomicAdd(&hist[d.x >> NPB_LOG], 1);
        atomicAdd(&hist[d.y >> NPB_LOG], 1);
        atomicAdd(&hist[d.z >> NPB_LOG], 1);
        atomicAdd(&hist[d.w >> NPB_LOG], 1);
    }
    for (int e = e0 + n4 * 4 + t; e < e1; e += 256)
        atomicAdd(&hist[dst[e] >> NPB_LOG], 1);
    __syncthreads();
    int h = hist[t];
    if (t < B && h) base[t] = atomicAdd(&cursorB[t], h);
    __syncthreads();
    hist[t] = 0;
    __syncthreads();
    for (int i = t; i < n4; i += 256) {
        uint4 d = d4[i0 + i];
        uint4 s = s4[i0 + i];
        int b0i = d.x >> NPB_LOG, b1i = d.y >> NPB_LOG, b2i = d.z >> NPB_LOG, b3i = d.w >> NPB_LOG;
        int o0 = atomicAdd(&hist[b0i], 1);
        ebuf[base[b0i] + o0] = (s.x << NPB_LOG) | (d.x & (NPB - 1));
        int o1 = atomicAdd(&hist[b1i], 1);
        ebuf[base[b1i] + o1] = (s.y << NPB_LOG) | (d.y & (NPB - 1));
        int o2 = atomicAdd(&hist[b2i], 1);
        ebuf[base[b2i] + o2] = (s.z << NPB_LOG) | (d.z & (NPB - 1));
        int o3 = atomicAdd(&hist[b3i], 1);
        ebuf[base[b3i] + o3] = (s.w << NPB_LOG) | (d.w & (NPB - 1));
    }
    for (int e = e0 + n4 * 4 + t; e < e1; e += 256) {
        int d = dst[e];
        int b = d >> NPB_LOG;
        int off = atomicAdd(&hist[b], 1);
        ebuf[base[b] + off] = ((unsigned)src[e] << NPB_LOG) | (unsigned)(d & (NPB - 1));
    }
}

__global__ __launch_bounds__(256) void build_csr_kernel(
    const unsigned* __restrict__ ebuf, const int* __restrict__ bstart,
    int* __restrict__ rowptr, float* __restrict__ degInv, int* __restrict__ csr,
    int N, int B) {
    __shared__ int cnt[NPB];
    __shared__ int cur[NPB];
    __shared__ int ps[256];
    int b = blockIdx.x;
    int t = threadIdx.x;
    int nbase = b << NPB_LOG;
    int nn = min(NPB, N - nbase);
    cnt[t] = 0;
    cnt[t + 256] = 0;
    __syncthreads();
    int ebeg = bstart[b], eend = bstart[b + 1];
    int eh = min((4 - (ebeg & 3)) & 3, eend - ebeg) + ebeg;
    for (int e = ebeg + t; e < eh; e += 256)
        atomicAdd(&cnt[ebuf[e] & (NPB - 1)], 1);
    int n4 = (eend - eh) >> 2;
    const uint4* p4 = reinterpret_cast<const uint4*>(ebuf + eh);
    for (int i = t; i < n4; i += 256) {
        uint4 p = p4[i];
        atomicAdd(&cnt[p.x & (NPB - 1)], 1);
        atomicAdd(&cnt[p.y & (NPB - 1)], 1);
        atomicAdd(&cnt[p.z & (NPB - 1)], 1);
        atomicAdd(&cnt[p.w & (NPB - 1)], 1);
    }
    for (int e = eh + n4 * 4 + t; e < eend; e += 256)
        atomicAdd(&cnt[ebuf[e] & (NPB - 1)], 1);
    __syncthreads();
    int c0 = cnt[2 * t], c1 = cnt[2 * t + 1];
    int pair = c0 + c1;
    ps[t] = pair;
    __syncthreads();
    for (int off = 1; off < 256; off <<= 1) {
        int x = ps[t];
        if (t >= off) x += ps[t - off];
        __syncthreads();
        ps[t] = x;
        __syncthreads();
    }
    int exPair = ps[t] - pair;
    int g0 = ebeg + exPair;
    int g1 = g0 + c0;
    cur[2 * t] = g0;
    cur[2 * t + 1] = g1;
    if (2 * t < nn) {
        rowptr[nbase + 2 * t] = g0;
        degInv[nbase + 2 * t] = 1.0f / (float)max(c0, 1);
    }
    if (2 * t + 1 < nn) {
        rowptr[nbase + 2 * t + 1] = g1;
        degInv[nbase + 2 * t + 1] = 1.0f / (float)max(c1, 1);
    }
    if (b == B - 1 && t == 0) rowptr[N] = eend;
    __syncthreads();
    for (int e = ebeg + t; e < eh; e += 256) {
        unsigned p = ebuf[e];
        int pos = atomicAdd(&cur[p & (NPB - 1)], 1);
        csr[pos] = (int)(p >> NPB_LOG);
    }
    for (int i = t; i < n4; i += 256) {
        uint4 p = p4[i];
        int pos;
        pos = atomicAdd(&cur[p.x & (NPB - 1)], 1); csr[pos] = (int)(p.x >> NPB_LOG);
        pos = atomicAdd(&cur[p.y & (NPB - 1)], 1); csr[pos] = (int)(p.y >> NPB_LOG);
        pos = atomicAdd(&cur[p.z & (NPB - 1)], 1); csr[pos] = (int)(p.z >> NPB_LOG);
        pos = atomicAdd(&cur[p.w & (NPB - 1)], 1); csr[pos] = (int)(p.w >> NPB_LOG);
    }
    for (int e = eh + n4 * 4 + t; e < eend; e += 256) {
        unsigned p = ebuf[e];
        int pos = atomicAdd(&cur[p & (NPB - 1)], 1);
        csr[pos] = (int)(p >> NPB_LOG);
    }
}

// ---------------- fused prep: weight swizzles + BN folds, one launch ----------------
__device__ __forceinline__ void swz_one(const float* __restrict__ Wl, const float* __restrict__ Wr,
                                        unsigned short* __restrict__ out, int CL, int CR, int id) {
    int C = CL + CR;
    int CT = C >> 4;
    int lane = id & 63;
    int ctkt = id >> 6;
    int ct = ctkt % CT;
    int kt = ctkt / CT;
    int col = ct * 16 + (lane & 15);
    int k0 = kt * 32 + (lane >> 4) * 8;
#pragma unroll
    for (int i = 0; i < 8; ++i) {
        int k = k0 + i;
        float w = (col < CL) ? Wl[(size_t)k * CL + col] : Wr[(size_t)k * CR + (col - CL)];
        out[(size_t)id * 8 + i] = (unsigned short)bf1(w);
    }
}

__global__ void prep_kernel(const float* __restrict__ Wl0, const float* __restrict__ Wr0,
                            const float* __restrict__ Wl1, const float* __restrict__ Wr1,
                            const float* __restrict__ Wl2, const float* __restrict__ Wr2,
                            const float* __restrict__ g0, const float* __restrict__ b0,
                            const float* __restrict__ m0, const float* __restrict__ v0,
                            const float* __restrict__ g1, const float* __restrict__ b1,
                            const float* __restrict__ m1, const float* __restrict__ v1,
                            unsigned short* __restrict__ Wsw0, unsigned short* __restrict__ Wsw1,
                            unsigned short* __restrict__ Wsw2,
                            float* __restrict__ bnA0, float* __restrict__ bnB0,
                            float* __restrict__ bnA1, float* __restrict__ bnB1) {
    int bid = blockIdx.x;
    int t = threadIdx.x;
    if (bid < 16) {
        swz_one(Wl0, Wr0, Wsw0, 128, 128, bid * 256 + t);
    } else if (bid < 32) {
        swz_one(Wl1, Wr1, Wsw1, 128, 128, (bid - 16) * 256 + t);
    } else if (bid < 40) {
        swz_one(Wl2, Wr2, Wsw2, 64, 64, (bid - 32) * 256 + t);
    } else {
        if (t < 128) {
            float A = g0[t] * rsqrtf(v0[t] + EPS);
            bnA0[t] = A;
            bnB0[t] = b0[t] - m0[t] * A;
        } else {
            int c = t - 128;
            float A = g1[c] * rsqrtf(v1[c] + EPS);
            bnA1[c] = A;
            bnB1[c] = b1[c] - m1[c] * A;
        }
    }
}

// ---------------- layer 0 GEMM (operand-swapped, LDS-staged f32 A): [tL|tR] = x @ [Wl|Wr] ----------------
__global__ __launch_bounds__(256, 4) void gemm0_kernel(
    const float* __restrict__ Af, const unsigned short* __restrict__ Wsw,
    const float* __restrict__ bl,
    unsigned char* __restrict__ tL, unsigned short* __restrict__ tR, int n) {
    constexpr int CT = 8;
    __shared__ unsigned short As[64][136];

    int tid = threadIdx.x;
    int lane = tid & 63;
    int wave = tid >> 6;
    int wr = wave >> 1, wc = wave & 1;
    int blk0 = blockIdx.x * 64;
    int rlo = lane & 15, kq = lane >> 4;

    {
        int srow = tid >> 2;
        int schunk = tid & 3;
        int grow = blk0 + srow;
        uint4 w0 = make_uint4(0, 0, 0, 0), w1 = w0, w2 = w0, w3 = w0;
        if (grow < n) {
            const float4* p = reinterpret_cast<const float4*>(Af + (size_t)grow * 128 + schunk * 32);
            float4 f0 = p[0], f1 = p[1], f2 = p[2], f3 = p[3];
            float4 f4 = p[4], f5 = p[5], f6 = p[6], f7 = p[7];
            w0 = make_uint4(pack2(f0.x, f0.y), pack2(f0.z, f0.w), pack2(f1.x, f1.y), pack2(f1.z, f1.w));
            w1 = make_uint4(pack2(f2.x, f2.y), pack2(f2.z, f2.w), pack2(f3.x, f3.y), pack2(f3.z, f3.w));
            w2 = make_uint4(pack2(f4.x, f4.y), pack2(f4.z, f4.w), pack2(f5.x, f5.y), pack2(f5.z, f5.w));
            w3 = make_uint4(pack2(f6.x, f6.y), pack2(f6.z, f6.w), pack2(f7.x, f7.y), pack2(f7.z, f7.w));
        }
        uint4* d = reinterpret_cast<uint4*>(&As[srow][schunk * 32]);
        d[0] = w0; d[1] = w1; d[2] = w2; d[3] = w3;
    }
    __syncthreads();

    f32x4 acc[2][CT];
#pragma unroll
    for (int nt = 0; nt < 2; ++nt)
#pragma unroll
        for (int c = 0; c < CT; ++c)
#pragma unroll
            for (int k = 0; k < 4; ++k) acc[nt][c][k] = 0.f;

    int lr0 = wr * 32 + rlo;
    int lr1 = wr * 32 + 16 + rlo;

    for (int kt = 0; kt < 4; ++kt) {
        int kb = kt * 32 + kq * 8;
        bf16x8 a0 = *reinterpret_cast<const bf16x8*>(&As[lr0][kb]);
        bf16x8 a1 = *reinterpret_cast<const bf16x8*>(&As[lr1][kb]);
#pragma unroll
        for (int c = 0; c < CT; ++c) {
            int ct_g = wc * CT + c;
            bf16x8 w = *reinterpret_cast<const bf16x8*>(Wsw + ((size_t)(kt * 2 * CT + ct_g) * 64 + lane) * 8);
            acc[0][c] = __builtin_amdgcn_mfma_f32_16x16x32_bf16(w, a0, acc[0][c], 0, 0, 0);
            acc[1][c] = __builtin_amdgcn_mfma_f32_16x16x32_bf16(w, a1, acc[1][c], 0, 0, 0);
        }
    }

#pragma unroll
    for (int nt = 0; nt < 2; ++nt) {
        int r = blk0 + wr * 32 + nt * 16 + rlo;
        if (r >= n) continue;
#pragma unroll
        for (int c = 0; c < CT; ++c) {
            int colbase = c * 16 + kq * 4;
            if (wc == 0) {
                unsigned w = __builtin_amdgcn_cvt_pk_fp8_f32(acc[nt][c][0], acc[nt][c][1], 0, false);
                w = __builtin_amdgcn_cvt_pk_fp8_f32(acc[nt][c][2], acc[nt][c][3], w, true);
                *reinterpret_cast<unsigned*>(tL + (size_t)r * 128 + colbase) = w;
            } else {
                float4 bv = *reinterpret_cast<const float4*>(bl + colbase);
                uint2 o;
                o.x = pack2(acc[nt][c][0] + bv.x, acc[nt][c][1] + bv.y);
                o.y = pack2(acc[nt][c][2] + bv.z, acc[nt][c][3] + bv.w);
                *reinterpret_cast<uint2*>(tR + (size_t)r * 128 + colbase) = o;
            }
        }
    }
}

// ---------------- fused aggregate->GEMM (v2: aggbn-shaped phase A, no spill) ----------------
// Phase A: 4 passes x (16 nodes x 16 lanes); per lane s[8] accum over 8-B fp8 loads (x8 unroll);
// result packed to one uint4 and written to the LDS h-tile.
// Phase B: operand-swapped MFMA identical to gemm0.
template <int CHALF>
__global__ __launch_bounds__(256) void fusedAG_kernel(
    const unsigned char* __restrict__ tLin, const unsigned short* __restrict__ tRin,
    const float* __restrict__ bnA, const float* __restrict__ bnB,
    const int* __restrict__ rowptr, const int* __restrict__ csr,
    const float* __restrict__ degInv,
    const unsigned short* __restrict__ Wsw, const float* __restrict__ bl,
    unsigned char* __restrict__ tLout, unsigned short* __restrict__ tRout, int n) {
    constexpr int CT = CHALF / 16;
    __shared__ unsigned short As[64][136];

    int tid = threadIdx.x;
    int blk0 = blockIdx.x * 64;
    int t = tid & 15;
    const uint2* T2 = reinterpret_cast<const uint2*>(tLin);

    // ---- phase A: gather + BN + ReLU -> LDS h-tile (4 passes of 16 nodes) ----
#pragma unroll
    for (int pass = 0; pass < 4; ++pass) {
        int lrow = pass * 16 + (tid >> 4);
        int v = blk0 + lrow;
        uint4* dst = reinterpret_cast<uint4*>(&As[lrow][t * 8]);
        if (v < n) {
            float s0 = 0.f, s1 = 0.f, s2 = 0.f, s3 = 0.f, s4 = 0.f, s5 = 0.f, s6 = 0.f, s7 = 0.f;
            int beg = rowptr[v], end = rowptr[v + 1];
            int e = beg;
            for (; e + 8 <= end; e += 8) {
                uint2 w0 = T2[(size_t)csr[e + 0] * 16 + t];
                uint2 w1 = T2[(size_t)csr[e + 1] * 16 + t];
                uint2 w2 = T2[(size_t)csr[e + 2] * 16 + t];
                uint2 w3 = T2[(size_t)csr[e + 3] * 16 + t];
                uint2 w4 = T2[(size_t)csr[e + 4] * 16 + t];
                uint2 w5 = T2[(size_t)csr[e + 5] * 16 + t];
                uint2 w6 = T2[(size_t)csr[e + 6] * 16 + t];
                uint2 w7 = T2[(size_t)csr[e + 7] * 16 + t];
                f32x2 p;
                p = fp8lo(w0.x); s0 += p[0]; s1 += p[1];
                p = fp8hi(w0.x); s2 += p[0]; s3 += p[1];
                p = fp8lo(w0.y); s4 += p[0]; s5 += p[1];
                p = fp8hi(w0.y); s6 += p[0]; s7 += p[1];
                p = fp8lo(w1.x); s0 += p[0]; s1 += p[1];
                p = fp8hi(w1.x); s2 += p[0]; s3 += p[1];
                p = fp8lo(w1.y); s4 += p[0]; s5 += p[1];
                p = fp8hi(w1.y); s6 += p[0]; s7 += p[1];
                p = fp8lo(w2.x); s0 += p[0]; s1 += p[1];
                p = fp8hi(w2.x); s2 += p[0]; s3 += p[1];
                p = fp8lo(w2.y); s4 += p[0]; s5 += p[1];
                p = fp8hi(w2.y); s6 += p[0]; s7 += p[1];
                p = fp8lo(w3.x); s0 += p[0]; s1 += p[1];
                p = fp8hi(w3.x); s2 += p[0]; s3 += p[1];
                p = fp8lo(w3.y); s4 += p[0]; s5 += p[1];
                p = fp8hi(w3.y); s6 += p[0]; s7 += p[1];
                p = fp8lo(w4.x); s0 += p[0]; s1 += p[1];
                p = fp8hi(w4.x); s2 += p[0]; s3 += p[1];
                p = fp8lo(w4.y); s4 += p[0]; s5 += p[1];
                p = fp8hi(w4.y); s6 += p[0]; s7 += p[1];
                p = fp8lo(w5.x); s0 += p[0]; s1 += p[1];
                p = fp8hi(w5.x); s2 += p[0]; s3 += p[1];
                p = fp8lo(w5.y); s4 += p[0]; s5 += p[1];
                p = fp8hi(w5.y); s6 += p[0]; s7 += p[1];
                p = fp8lo(w6.x); s0 += p[0]; s1 += p[1];
                p = fp8hi(w6.x); s2 += p[0]; s3 += p[1];
                p = fp8lo(w6.y); s4 += p[0]; s5 += p[1];
                p = fp8hi(w6.y); s6 += p[0]; s7 += p[1];
                p = fp8lo(w7.x); s0 += p[0]; s1 += p[1];
                p = fp8hi(w7.x); s2 += p[0]; s3 += p[1];
                p = fp8lo(w7.y); s4 += p[0]; s5 += p[1];
                p = fp8hi(w7.y); s6 += p[0]; s7 += p[1];
            }
            for (; e < end; ++e) {
                uint2 w = T2[(size_t)csr[e] * 16 + t];
                f32x2 p;
                p = fp8lo(w.x); s0 += p[0]; s1 += p[1];
                p = fp8hi(w.x); s2 += p[0]; s3 += p[1];
                p = fp8lo(w.y); s4 += p[0]; s5 += p[1];
                p = fp8hi(w.y); s6 += p[0]; s7 += p[1];
            }
            float di = degInv[v];
            uint4 rw = reinterpret_cast<const uint4*>(tRin)[(size_t)v * 16 + t];
            float4 A0 = reinterpret_cast<const float4*>(bnA + t * 8)[0];
            float4 A1 = reinterpret_cast<const float4*>(bnA + t * 8)[1];
            float4 B0 = reinterpret_cast<const float4*>(bnB + t * 8)[0];
            float4 B1 = reinterpret_cast<const float4*>(bnB + t * 8)[1];
            float h0 = fmaxf(A0.x * (s0 * di + blo(rw.x)) + B0.x, 0.f);
            float h1 = fmaxf(A0.y * (s1 * di + bhi(rw.x)) + B0.y, 0.f);
            float h2 = fmaxf(A0.z * (s2 * di + blo(rw.y)) + B0.z, 0.f);
            float h3 = fmaxf(A0.w * (s3 * di + bhi(rw.y)) + B0.w, 0.f);
            float h4 = fmaxf(A1.x * (s4 * di + blo(rw.z)) + B1.x, 0.f);
            float h5 = fmaxf(A1.y * (s5 * di + bhi(rw.z)) + B1.y, 0.f);
            float h6 = fmaxf(A1.z * (s6 * di + blo(rw.w)) + B1.z, 0.f);
            float h7 = fmaxf(A1.w * (s7 * di + bhi(rw.w)) + B1.w, 0.f);
            uint4 o;
            o.x = pack2(h0, h1);
            o.y = pack2(h2, h3);
            o.z = pack2(h4, h5);
            o.w = pack2(h6, h7);
            *dst = o;
        } else {
            *dst = make_uint4(0, 0, 0, 0);
        }
    }
    __syncthreads();

    // ---- phase B: MFMA ----
    int lane = tid & 63;
    int wave = tid >> 6;
    int wr = wave >> 1, wc = wave & 1;
    int rlo = lane & 15, kq = lane >> 4;

    f32x4 acc[2][CT];
#pragma unroll
    for (int nt = 0; nt < 2; ++nt)
#pragma unroll
        for (int c = 0; c < CT; ++c)
#pragma unroll
            for (int k = 0; k < 4; ++k) acc[nt][c][k] = 0.f;

    int lr0 = wr * 32 + rlo;
    int lr1 = wr * 32 + 16 + rlo;

    for (int kt = 0; kt < 4; ++kt) {
        int kb = kt * 32 + kq * 8;
        bf16x8 a0 = *reinterpret_cast<const bf16x8*>(&As[lr0][kb]);
        bf16x8 a1 = *reinterpret_cast<const bf16x8*>(&As[lr1][kb]);
#pragma unroll
        for (int c = 0; c < CT; ++c) {
            int ct_g = wc * CT + c;
            bf16x8 w = *reinterpret_cast<const bf16x8*>(Wsw + ((size_t)(kt * 2 * CT + ct_g) * 64 + lane) * 8);
            acc[0][c] = __builtin_amdgcn_mfma_f32_16x16x32_bf16(w, a0, acc[0][c], 0, 0, 0);
            acc[1][c] = __builtin_amdgcn_mfma_f32_16x16x32_bf16(w, a1, acc[1][c], 0, 0, 0);
        }
    }

#pragma unroll
    for (int nt = 0; nt < 2; ++nt) {
        int r = blk0 + wr * 32 + nt * 16 + rlo;
        if (r >= n) continue;
#pragma unroll
        for (int c = 0; c < CT; ++c) {
            int colbase = c * 16 + kq * 4;
            if (wc == 0) {
                unsigned w = __builtin_amdgcn_cvt_pk_fp8_f32(acc[nt][c][0], acc[nt][c][1], 0, false);
                w = __builtin_amdgcn_cvt_pk_fp8_f32(acc[nt][c][2], acc[nt][c][3], w, true);
                *reinterpret_cast<unsigned*>(tLout + (size_t)r * CHALF + colbase) = w;
            } else {
                float4 bv = *reinterpret_cast<const float4*>(bl + colbase);
                uint2 o;
                o.x = pack2(acc[nt][c][0] + bv.x, acc[nt][c][1] + bv.y);
                o.y = pack2(acc[nt][c][2] + bv.z, acc[nt][c][3] + bv.w);
                *reinterpret_cast<uint2*>(tRout + (size_t)r * CHALF + colbase) = o;
            }
        }
    }
}

// ---------------- final: out = log_softmax( mean-agg(tL2 fp8) + tR2 bf16 ) ----------------
__global__ void agg64_lsm_kernel(const unsigned char* __restrict__ tL2,
                                 const unsigned short* __restrict__ tR2,
                                 const int* __restrict__ rowptr, const int* __restrict__ csr,
                                 const float* __restrict__ degInv,
                                 float* __restrict__ out, int n) {
    int idx = blockIdx.x * blockDim.x + threadIdx.x;
    int v = idx >> 3;
    int t = idx & 7;
    if (v >= n) return;
    int beg = rowptr[v], end = rowptr[v + 1];
    const uint2* T2 = reinterpret_cast<const uint2*>(tL2);
    float s0 = 0.f, s1 = 0.f, s2 = 0.f, s3 = 0.f, s4 = 0.f, s5 = 0.f, s6 = 0.f, s7 = 0.f;
    int e = beg;
    for (; e + 8 <= end; e += 8) {
        uint2 w0 = T2[(size_t)csr[e + 0] * 8 + t];
        uint2 w1 = T2[(size_t)csr[e + 1] * 8 + t];
        uint2 w2 = T2[(size_t)csr[e + 2] * 8 + t];
        uint2 w3 = T2[(size_t)csr[e + 3] * 8 + t];
        uint2 w4 = T2[(size_t)csr[e + 4] * 8 + t];
        uint2 w5 = T2[(size_t)csr[e + 5] * 8 + t];
        uint2 w6 = T2[(size_t)csr[e + 6] * 8 + t];
        uint2 w7 = T2[(size_t)csr[e + 7] * 8 + t];
        f32x2 p;
        p = fp8lo(w0.x); s0 += p[0]; s1 += p[1];
        p = fp8hi(w0.x); s2 += p[0]; s3 += p[1];
        p = fp8lo(w0.y); s4 += p[0]; s5 += p[1];
        p = fp8hi(w0.y); s6 += p[0]; s7 += p[1];
        p = fp8lo(w1.x); s0 += p[0]; s1 += p[1];
        p = fp8hi(w1.x); s2 += p[0]; s3 += p[1];
        p = fp8lo(w1.y); s4 += p[0]; s5 += p[1];
        p = fp8hi(w1.y); s6 += p[0]; s7 += p[1];
        p = fp8lo(w2.x); s0 += p[0]; s1 += p[1];
        p = fp8hi(w2.x); s2 += p[0]; s3 += p[1];
        p = fp8lo(w2.y); s4 += p[0]; s5 += p[1];
        p = fp8hi(w2.y); s6 += p[0]; s7 += p[1];
        p = fp8lo(w3.x); s0 += p[0]; s1 += p[1];
        p = fp8hi(w3.x); s2 += p[0]; s3 += p[1];
        p = fp8lo(w3.y); s4 += p[0]; s5 += p[1];
        p = fp8hi(w3.y); s6 += p[0]; s7 += p[1];
        p = fp8lo(w4.x); s0 += p[0]; s1 += p[1];
        p = fp8hi(w4.x); s2 += p[0]; s3 += p[1];
        p = fp8lo(w4.y); s4 += p[0]; s5 += p[1];
        p = fp8hi(w4.y); s6 += p[0]; s7 += p[1];
        p = fp8lo(w5.x); s0 += p[0]; s1 += p[1];
        p = fp8hi(w5.x); s2 += p[0]; s3 += p[1];
        p = fp8lo(w5.y); s4 += p[0]; s5 += p[1];
        p = fp8hi(w5.y); s6 += p[0]; s7 += p[1];
        p = fp8lo(w6.x); s0 += p[0]; s1 += p[1];
        p = fp8hi(w6.x); s2 += p[0]; s3 += p[1];
        p = fp8lo(w6.y); s4 += p[0]; s5 += p[1];
        p = fp8hi(w6.y); s6 += p[0]; s7 += p[1];
        p = fp8lo(w7.x); s0 += p[0]; s1 += p[1];
        p = fp8hi(w7.x); s2 += p[0]; s3 += p[1];
        p = fp8lo(w7.y); s4 += p[0]; s5 += p[1];
        p = fp8hi(w7.y); s6 += p[0]; s7 += p[1];
    }
    for (; e < end; ++e) {
        uint2 w = T2[(size_t)csr[e] * 8 + t];
        f32x2 p;
        p = fp8lo(w.x); s0 += p[0]; s1 += p[1];
        p = fp8hi(w.x); s2 += p[0]; s3 += p[1];
        p = fp8lo(w.y); s4 += p[0]; s5 += p[1];
        p = fp8hi(w.y); s6 += p[0]; s7 += p[1];
    }
    float di = degInv[v];
    uint4 rw = reinterpret_cast<const uint4*>(tR2)[(size_t)v * 8 + t];
    float y0 = s0 * di + blo(rw.x);
    float y1 = s1 * di + bhi(rw.x);
    float y2 = s2 * di + blo(rw.y);
    float y3 = s3 * di + bhi(rw.y);
    float y4 = s4 * di + blo(rw.z);
    float y5 = s5 * di + bhi(rw.z);
    float y6 = s6 * di + blo(rw.w);
    float y7 = s7 * di + bhi(rw.w);

    float mx = fmaxf(fmaxf(fmaxf(y0, y1), fmaxf(y2, y3)),
                     fmaxf(fmaxf(y4, y5), fmaxf(y6, y7)));
#pragma unroll
    for (int o = 1; o < 8; o <<= 1) mx = fmaxf(mx, __shfl_xor(mx, o));
    float s = __expf(y0 - mx) + __expf(y1 - mx) + __expf(y2 - mx) + __expf(y3 - mx)
            + __expf(y4 - mx) + __expf(y5 - mx) + __expf(y6 - mx) + __expf(y7 - mx);
#pragma unroll
    for (int o = 1; o < 8; o <<= 1) s += __shfl_xor(s, o);
    float lse = mx + __logf(s);

    float4 oA, oB;
    oA.x = y0 - lse; oA.y = y1 - lse; oA.z = y2 - lse; oA.w = y3 - lse;
    oB.x = y4 - lse; oB.y = y5 - lse; oB.z = y6 - lse; oB.w = y7 - lse;
    float4* O4 = reinterpret_cast<float4*>(out + (size_t)v * 64 + t * 8);
    O4[0] = oA;
    O4[1] = oB;
}

// ---------------- launch ----------------

extern "C" void kernel_launch(void* const* d_in, const int* in_sizes, int n_in,
                              void* d_out, int out_size, void* d_ws, size_t ws_size,
                              hipStream_t stream) {
    const float* x   = (const float*)d_in[0];
    const int*   ei  = (const int*)d_in[1];
    const float* Wl0 = (const float*)d_in[2];
    const float* bl0 = (const float*)d_in[3];
    const float* Wr0 = (const float*)d_in[4];
    const float* g0  = (const float*)d_in[5];
    const float* b0  = (const float*)d_in[6];
    const float* m0  = (const float*)d_in[7];
    const float* v0  = (const float*)d_in[8];
    const float* Wl1 = (const float*)d_in[9];
    const float* bl1 = (const float*)d_in[10];
    const float* Wr1 = (const float*)d_in[11];
    const float* g1  = (const float*)d_in[12];
    const float* b1  = (const float*)d_in[13];
    const float* m1  = (const float*)d_in[14];
    const float* v1  = (const float*)d_in[15];
    const float* Wl2 = (const float*)d_in[16];
    const float* bl2 = (const float*)d_in[17];
    const float* Wr2 = (const float*)d_in[18];
    float* out = (float*)d_out;

    const int N = in_sizes[0] / 128;
    const int E = in_sizes[1] / 2;
    const int B = (N + NPB - 1) >> NPB_LOG;
    const int* src = ei;
    const int* dst = ei + E;

    char* ws = (char*)d_ws;
    size_t off = 0;
    auto alloc = [&](size_t bytes) -> void* {
        void* p = ws + off;
        off += (bytes + 255) & ~(size_t)255;
        return p;
    };
    int*   bcnt    = (int*)alloc(256 * 4);
    int*   bstart  = (int*)alloc(257 * 4);
    int*   cursorB = (int*)alloc(256 * 4);
    int*   rowptr  = (int*)alloc((size_t)(N + 1) * 4);
    float* degInv  = (float*)alloc((size_t)N * 4);
    int*   csr     = (int*)alloc((size_t)E * 4);
    unsigned* ebuf = (unsigned*)alloc((size_t)E * 4);
    unsigned char*  tLa = (unsigned char*)alloc((size_t)N * 128);        // fp8  [N][128] layer0
    unsigned short* tRa = (unsigned short*)alloc((size_t)N * 128 * 2);   // bf16 [N][128] layer0
    unsigned char*  tLb = (unsigned char*)alloc((size_t)N * 128);        // fp8  [N][128] layer1
    unsigned short* tRb = (unsigned short*)alloc((size_t)N * 128 * 2);   // bf16 [N][128] layer1
    unsigned short* Wsw0 = (unsigned short*)alloc(4 * 16 * 64 * 8 * 2);
    unsigned short* Wsw1 = (unsigned short*)alloc(4 * 16 * 64 * 8 * 2);
    unsigned short* Wsw2 = (unsigned short*)alloc(4 * 8 * 64 * 8 * 2);
    float* bnA0 = (float*)alloc(128 * 4);
    float* bnB0 = (float*)alloc(128 * 4);
    float* bnA1 = (float*)alloc(128 * 4);
    float* bnB1 = (float*)alloc(128 * 4);
    unsigned char*  tL2 = tLa;                           // fp8  [N][64] overlays tLa
    unsigned short* tR2 = tRa;                           // bf16 [N][64] overlays tRa

    hipMemsetAsync(bcnt, 0, 256 * 4, stream);

    // CSR build + prep
    bucket_hist_kernel<<<512, 256, 0, stream>>>(dst, bcnt, E, B);
    bucket_scan_kernel<<<1, 256, 0, stream>>>(bcnt, bstart, cursorB, B, E);
    partition_kernel<<<(E + 4095) / 4096, 256, 0, stream>>>(src, dst, cursorB, ebuf, E, B);
    build_csr_kernel<<<B, 256, 0, stream>>>(ebuf, bstart, rowptr, degInv, csr, N, B);
    prep_kernel<<<41, 256, 0, stream>>>(Wl0, Wr0, Wl1, Wr1, Wl2, Wr2,
                                        g0, b0, m0, v0, g1, b1, m1, v1,
                                        Wsw0, Wsw1, Wsw2, bnA0, bnB0, bnA1, bnB1);

    int gemmGrid = (N + 63) / 64;
    int lsmGrid = (int)(((size_t)N * 8 + 255) / 256);

    // layer 0: [tLa|tRa] = x @ [Wl0|Wr0]  (tLa fp8, tRa bf16 with +bl0)
    gemm0_kernel<<<gemmGrid, 256, 0, stream>>>(x, Wsw0, bl0, tLa, tRa, N);
    // layer 1 fused: h0 = ReLU(BN0(agg(tLa)+tRa)) in LDS; [tLb|tRb] = h0 @ [Wl1|Wr1]
    fusedAG_kernel<128><<<gemmGrid, 256, 0, stream>>>(
        tLa, tRa, bnA0, bnB0, rowptr, csr, degInv, Wsw1, bl1, tLb, tRb, N);
    // layer 2 fused: h1 = ReLU(BN1(agg(tLb)+tRb)) in LDS; [tL2|tR2] = h1 @ [Wl2|Wr2]
    fusedAG_kernel<64><<<gemmGrid, 256, 0, stream>>>(
        tLb, tRb, bnA1, bnB1, rowptr, csr, degInv, Wsw2, bl2, tL2, tR2, N);
    // final: out = log_softmax(agg(tL2) + tR2)
    agg64_lsm_kernel<<<lsmGrid, 256, 0, stream>>>(tL2, tR2, rowptr, csr, degInv, out, N);
}

// Round 14
// 246.835 us; speedup vs baseline: 1.6767x; 1.3857x over previous
//
#include <hip/hip_runtime.h>

constexpr float EPS = 1e-5f;

#define NPB_LOG 9
#define NPB 512

typedef __attribute__((ext_vector_type(8))) __bf16 bf16x8;
typedef __attribute__((ext_vector_type(4))) float f32x4;
typedef __attribute__((ext_vector_type(2))) float f32x2;

// ---------- bf16 helpers ----------
__device__ __forceinline__ float blo(unsigned u) { return __uint_as_float(u << 16); }
__device__ __forceinline__ float bhi(unsigned u) { return __uint_as_float(u & 0xffff0000u); }
__device__ __forceinline__ unsigned bf1(float f) {
    unsigned u = __float_as_uint(f);
    return (u + 0x7fffu + ((u >> 16) & 1u)) >> 16;
}
__device__ __forceinline__ unsigned pack2(float a, float b) { return bf1(a) | (bf1(b) << 16); }

// ---------- fp8 helpers ----------
__device__ __forceinline__ f32x2 fp8lo(unsigned w) {
    return __builtin_amdgcn_cvt_pk_f32_fp8(w, false);
}
__device__ __forceinline__ f32x2 fp8hi(unsigned w) {
    return __builtin_amdgcn_cvt_pk_f32_fp8(w, true);
}

// ---------------- CSR build (locality-aware, uint4-vectorized edge reads) ----------------

__global__ void bucket_hist_kernel(const int* __restrict__ dst, int* __restrict__ bcnt,
                                   int E, int B) {
    __shared__ int h[256];
    int t = threadIdx.x;
    h[t] = 0;
    __syncthreads();
    int E4 = E >> 2;
    const uint4* d4 = reinterpret_cast<const uint4*>(dst);
    for (int i = blockIdx.x * blockDim.x + t; i < E4; i += gridDim.x * blockDim.x) {
        uint4 d = d4[i];
        atomicAdd(&h[d.x >> NPB_LOG], 1);
        atomicAdd(&h[d.y >> NPB_LOG], 1);
        atomicAdd(&h[d.z >> NPB_LOG], 1);
        atomicAdd(&h[d.w >> NPB_LOG], 1);
    }
    if (blockIdx.x == 0 && t < (E & 3))
        atomicAdd(&h[dst[E4 * 4 + t] >> NPB_LOG], 1);
    __syncthreads();
    if (t < B && h[t]) atomicAdd(&bcnt[t], h[t]);
}

__global__ void bucket_scan_kernel(const int* __restrict__ bcnt, int* __restrict__ bstart,
                                   int* __restrict__ cursorB, int B, int E) {
    __shared__ int tmp[256];
    int t = threadIdx.x;
    int v = (t < B) ? bcnt[t] : 0;
    tmp[t] = v;
    __syncthreads();
    for (int off = 1; off < 256; off <<= 1) {
        int x = tmp[t];
        if (t >= off) x += tmp[t - off];
        __syncthreads();
        tmp[t] = x;
        __syncthreads();
    }
    if (t < B) {
        int ex = tmp[t] - v;
        bstart[t] = ex;
        cursorB[t] = ex;
    }
    if (t == 0) bstart[B] = E;
}

__global__ __launch_bounds__(256) void partition_kernel(
    const int* __restrict__ src, const int* __restrict__ dst,
    int* __restrict__ cursorB, unsigned* __restrict__ ebuf, int E, int B) {
    __shared__ int hist[256];
    __shared__ int base[256];
    int t = threadIdx.x;
    hist[t] = 0;
    __syncthreads();
    int e0 = blockIdx.x * 4096;
    int e1 = min(e0 + 4096, E);
    const uint4* d4 = reinterpret_cast<const uint4*>(dst);
    const uint4* s4 = reinterpret_cast<const uint4*>(src);
    int n4 = (e1 - e0) >> 2;
    int i0 = e0 >> 2;
    for (int i = t; i < n4; i += 256) {
        uint4 d = d4[i0 + i];
        atomicAdd(&hist[d.x >> NPB_LOG], 1);
        atomicAdd(&hist[d.y >> NPB_LOG], 1);
        atomicAdd(&hist[d.z >> NPB_LOG], 1);
        atomicAdd(&hist[d.w >> NPB_LOG], 1);
    }
    for (int e = e0 + n4 * 4 + t; e < e1; e += 256)
        atomicAdd(&hist[dst[e] >> NPB_LOG], 1);
    __syncthreads();
    int h = hist[t];
    if (t < B && h) base[t] = atomicAdd(&cursorB[t], h);
    __syncthreads();
    hist[t] = 0;
    __syncthreads();
    for (int i = t; i < n4; i += 256) {
        uint4 d = d4[i0 + i];
        uint4 s = s4[i0 + i];
        int b0i = d.x >> NPB_LOG, b1i = d.y >> NPB_LOG, b2i = d.z >> NPB_LOG, b3i = d.w >> NPB_LOG;
        int o0 = atomicAdd(&hist[b0i], 1);
        ebuf[base[b0i] + o0] = (s.x << NPB_LOG) | (d.x & (NPB - 1));
        int o1 = atomicAdd(&hist[b1i], 1);
        ebuf[base[b1i] + o1] = (s.y << NPB_LOG) | (d.y & (NPB - 1));
        int o2 = atomicAdd(&hist[b2i], 1);
        ebuf[base[b2i] + o2] = (s.z << NPB_LOG) | (d.z & (NPB - 1));
        int o3 = atomicAdd(&hist[b3i], 1);
        ebuf[base[b3i] + o3] = (s.w << NPB_LOG) | (d.w & (NPB - 1));
    }
    for (int e = e0 + n4 * 4 + t; e < e1; e += 256) {
        int d = dst[e];
        int b = d >> NPB_LOG;
        int off = atomicAdd(&hist[b], 1);
        ebuf[base[b] + off] = ((unsigned)src[e] << NPB_LOG) | (unsigned)(d & (NPB - 1));
    }
}

__global__ __launch_bounds__(256) void build_csr_kernel(
    const unsigned* __restrict__ ebuf, const int* __restrict__ bstart,
    int* __restrict__ rowptr, float* __restrict__ degInv, int* __restrict__ csr,
    int N, int B) {
    __shared__ int cnt[NPB];
    __shared__ int cur[NPB];
    __shared__ int ps[256];
    int b = blockIdx.x;
    int t = threadIdx.x;
    int nbase = b << NPB_LOG;
    int nn = min(NPB, N - nbase);
    cnt[t] = 0;
    cnt[t + 256] = 0;
    __syncthreads();
    int ebeg = bstart[b], eend = bstart[b + 1];
    int eh = min((4 - (ebeg & 3)) & 3, eend - ebeg) + ebeg;
    for (int e = ebeg + t; e < eh; e += 256)
        atomicAdd(&cnt[ebuf[e] & (NPB - 1)], 1);
    int n4 = (eend - eh) >> 2;
    const uint4* p4 = reinterpret_cast<const uint4*>(ebuf + eh);
    for (int i = t; i < n4; i += 256) {
        uint4 p = p4[i];
        atomicAdd(&cnt[p.x & (NPB - 1)], 1);
        atomicAdd(&cnt[p.y & (NPB - 1)], 1);
        atomicAdd(&cnt[p.z & (NPB - 1)], 1);
        atomicAdd(&cnt[p.w & (NPB - 1)], 1);
    }
    for (int e = eh + n4 * 4 + t; e < eend; e += 256)
        atomicAdd(&cnt[ebuf[e] & (NPB - 1)], 1);
    __syncthreads();
    int c0 = cnt[2 * t], c1 = cnt[2 * t + 1];
    int pair = c0 + c1;
    ps[t] = pair;
    __syncthreads();
    for (int off = 1; off < 256; off <<= 1) {
        int x = ps[t];
        if (t >= off) x += ps[t - off];
        __syncthreads();
        ps[t] = x;
        __syncthreads();
    }
    int exPair = ps[t] - pair;
    int g0 = ebeg + exPair;
    int g1 = g0 + c0;
    cur[2 * t] = g0;
    cur[2 * t + 1] = g1;
    if (2 * t < nn) {
        rowptr[nbase + 2 * t] = g0;
        degInv[nbase + 2 * t] = 1.0f / (float)max(c0, 1);
    }
    if (2 * t + 1 < nn) {
        rowptr[nbase + 2 * t + 1] = g1;
        degInv[nbase + 2 * t + 1] = 1.0f / (float)max(c1, 1);
    }
    if (b == B - 1 && t == 0) rowptr[N] = eend;
    __syncthreads();
    for (int e = ebeg + t; e < eh; e += 256) {
        unsigned p = ebuf[e];
        int pos = atomicAdd(&cur[p & (NPB - 1)], 1);
        csr[pos] = (int)(p >> NPB_LOG);
    }
    for (int i = t; i < n4; i += 256) {
        uint4 p = p4[i];
        int pos;
        pos = atomicAdd(&cur[p.x & (NPB - 1)], 1); csr[pos] = (int)(p.x >> NPB_LOG);
        pos = atomicAdd(&cur[p.y & (NPB - 1)], 1); csr[pos] = (int)(p.y >> NPB_LOG);
        pos = atomicAdd(&cur[p.z & (NPB - 1)], 1); csr[pos] = (int)(p.z >> NPB_LOG);
        pos = atomicAdd(&cur[p.w & (NPB - 1)], 1); csr[pos] = (int)(p.w >> NPB_LOG);
    }
    for (int e = eh + n4 * 4 + t; e < eend; e += 256) {
        unsigned p = ebuf[e];
        int pos = atomicAdd(&cur[p & (NPB - 1)], 1);
        csr[pos] = (int)(p >> NPB_LOG);
    }
}

// ---------------- fused prep: weight swizzles + BN folds, one launch ----------------
__device__ __forceinline__ void swz_one(const float* __restrict__ Wl, const float* __restrict__ Wr,
                                        unsigned short* __restrict__ out, int CL, int CR, int id) {
    int C = CL + CR;
    int CT = C >> 4;
    int lane = id & 63;
    int ctkt = id >> 6;
    int ct = ctkt % CT;
    int kt = ctkt / CT;
    int col = ct * 16 + (lane & 15);
    int k0 = kt * 32 + (lane >> 4) * 8;
#pragma unroll
    for (int i = 0; i < 8; ++i) {
        int k = k0 + i;
        float w = (col < CL) ? Wl[(size_t)k * CL + col] : Wr[(size_t)k * CR + (col - CL)];
        out[(size_t)id * 8 + i] = (unsigned short)bf1(w);
    }
}

__global__ void prep_kernel(const float* __restrict__ Wl0, const float* __restrict__ Wr0,
                            const float* __restrict__ Wl1, const float* __restrict__ Wr1,
                            const float* __restrict__ Wl2, const float* __restrict__ Wr2,
                            const float* __restrict__ g0, const float* __restrict__ b0,
                            const float* __restrict__ m0, const float* __restrict__ v0,
                            const float* __restrict__ g1, const float* __restrict__ b1,
                            const float* __restrict__ m1, const float* __restrict__ v1,
                            unsigned short* __restrict__ Wsw0, unsigned short* __restrict__ Wsw1,
                            unsigned short* __restrict__ Wsw2,
                            float* __restrict__ bnA0, float* __restrict__ bnB0,
                            float* __restrict__ bnA1, float* __restrict__ bnB1) {
    int bid = blockIdx.x;
    int t = threadIdx.x;
    if (bid < 16) {
        swz_one(Wl0, Wr0, Wsw0, 128, 128, bid * 256 + t);
    } else if (bid < 32) {
        swz_one(Wl1, Wr1, Wsw1, 128, 128, (bid - 16) * 256 + t);
    } else if (bid < 40) {
        swz_one(Wl2, Wr2, Wsw2, 64, 64, (bid - 32) * 256 + t);
    } else {
        if (t < 128) {
            float A = g0[t] * rsqrtf(v0[t] + EPS);
            bnA0[t] = A;
            bnB0[t] = b0[t] - m0[t] * A;
        } else {
            int c = t - 128;
            float A = g1[c] * rsqrtf(v1[c] + EPS);
            bnA1[c] = A;
            bnB1[c] = b1[c] - m1[c] * A;
        }
    }
}

// ---------------- MFMA GEMM (operand-swapped, LDS-staged A): [tL|tR] = A @ [Wl|Wr] ----------------
// A-tile (64 rows x 128 cols) staged once per block via coalesced 64B/thread loads;
// +8-element row pad makes ds_read_b128 fragments <=2-way bank aliased (free).
// wc=0 waves -> tL (fp8, dword stores), wc=1 -> tR (+bl, bf16 uint2 stores).
template <int CHALF, bool AF32>
__global__ __launch_bounds__(256, 4) void gemmT_kernel(
    const void* __restrict__ Av, const unsigned short* __restrict__ Wsw,
    const float* __restrict__ bl,
    unsigned char* __restrict__ tL, unsigned short* __restrict__ tR, int n) {
    constexpr int CT = CHALF / 16;
    __shared__ unsigned short As[64][136];   // 272-B row stride (16B-aligned, pad kills conflicts)

    int tid = threadIdx.x;
    int lane = tid & 63;
    int wave = tid >> 6;
    int wr = wave >> 1, wc = wave & 1;
    int blk0 = blockIdx.x * 64;
    int rlo = lane & 15, kq = lane >> 4;

    // ---- stage A tile (rows >= n zero-filled) ----
    {
        int srow = tid >> 2;          // 0..63
        int schunk = tid & 3;         // 0..3, 32 elements each
        int grow = blk0 + srow;
        uint4 w0 = make_uint4(0, 0, 0, 0), w1 = w0, w2 = w0, w3 = w0;
        if (grow < n) {
            if (AF32) {
                const float* Af = (const float*)Av;
                const float4* p = reinterpret_cast<const float4*>(Af + (size_t)grow * 128 + schunk * 32);
                float4 f0 = p[0], f1 = p[1], f2 = p[2], f3 = p[3];
                float4 f4 = p[4], f5 = p[5], f6 = p[6], f7 = p[7];
                w0 = make_uint4(pack2(f0.x, f0.y), pack2(f0.z, f0.w), pack2(f1.x, f1.y), pack2(f1.z, f1.w));
                w1 = make_uint4(pack2(f2.x, f2.y), pack2(f2.z, f2.w), pack2(f3.x, f3.y), pack2(f3.z, f3.w));
                w2 = make_uint4(pack2(f4.x, f4.y), pack2(f4.z, f4.w), pack2(f5.x, f5.y), pack2(f5.z, f5.w));
                w3 = make_uint4(pack2(f6.x, f6.y), pack2(f6.z, f6.w), pack2(f7.x, f7.y), pack2(f7.z, f7.w));
            } else {
                const unsigned short* A = (const unsigned short*)Av;
                const uint4* p = reinterpret_cast<const uint4*>(A + (size_t)grow * 128 + schunk * 32);
                w0 = p[0]; w1 = p[1]; w2 = p[2]; w3 = p[3];
            }
        }
        uint4* d = reinterpret_cast<uint4*>(&As[srow][schunk * 32]);
        d[0] = w0; d[1] = w1; d[2] = w2; d[3] = w3;
    }
    __syncthreads();

    f32x4 acc[2][CT];
#pragma unroll
    for (int nt = 0; nt < 2; ++nt)
#pragma unroll
        for (int c = 0; c < CT; ++c)
#pragma unroll
            for (int k = 0; k < 4; ++k) acc[nt][c][k] = 0.f;

    int lr0 = wr * 32 + rlo;
    int lr1 = wr * 32 + 16 + rlo;

    for (int kt = 0; kt < 4; ++kt) {
        int kb = kt * 32 + kq * 8;
        bf16x8 a0 = *reinterpret_cast<const bf16x8*>(&As[lr0][kb]);
        bf16x8 a1 = *reinterpret_cast<const bf16x8*>(&As[lr1][kb]);
#pragma unroll
        for (int c = 0; c < CT; ++c) {
            int ct_g = wc * CT + c;
            bf16x8 w = *reinterpret_cast<const bf16x8*>(Wsw + ((size_t)(kt * 2 * CT + ct_g) * 64 + lane) * 8);
            acc[0][c] = __builtin_amdgcn_mfma_f32_16x16x32_bf16(w, a0, acc[0][c], 0, 0, 0);
            acc[1][c] = __builtin_amdgcn_mfma_f32_16x16x32_bf16(w, a1, acc[1][c], 0, 0, 0);
        }
    }

#pragma unroll
    for (int nt = 0; nt < 2; ++nt) {
        int r = blk0 + wr * 32 + nt * 16 + rlo;
        if (r >= n) continue;
#pragma unroll
        for (int c = 0; c < CT; ++c) {
            int colbase = c * 16 + kq * 4;
            if (wc == 0) {
                unsigned w = __builtin_amdgcn_cvt_pk_fp8_f32(acc[nt][c][0], acc[nt][c][1], 0, false);
                w = __builtin_amdgcn_cvt_pk_fp8_f32(acc[nt][c][2], acc[nt][c][3], w, true);
                *reinterpret_cast<unsigned*>(tL + (size_t)r * CHALF + colbase) = w;
            } else {
                float4 bv = *reinterpret_cast<const float4*>(bl + colbase);
                uint2 o;
                o.x = pack2(acc[nt][c][0] + bv.x, acc[nt][c][1] + bv.y);
                o.y = pack2(acc[nt][c][2] + bv.z, acc[nt][c][3] + bv.w);
                *reinterpret_cast<uint2*>(tR + (size_t)r * CHALF + colbase) = o;
            }
        }
    }
}

// ---------------- aggregate fp8 tL (128-B rows) + tR + BN + ReLU -> h bf16 ----------------
// 16 lanes/node, 8 B per lane, x8-deep independent gathers.
__global__ void aggbn_kernel(const unsigned char* __restrict__ tL,
                             const unsigned short* __restrict__ tR,
                             const float* __restrict__ bnA, const float* __restrict__ bnB,
                             const int* __restrict__ rowptr, const int* __restrict__ csr,
                             const float* __restrict__ degInv,
                             unsigned short* __restrict__ h, int n) {
    int idx = blockIdx.x * blockDim.x + threadIdx.x;
    int v = idx >> 4;
    int t = idx & 15;
    if (v >= n) return;
    int beg = rowptr[v], end = rowptr[v + 1];
    const uint2* T2 = reinterpret_cast<const uint2*>(tL);
    float s0 = 0.f, s1 = 0.f, s2 = 0.f, s3 = 0.f, s4 = 0.f, s5 = 0.f, s6 = 0.f, s7 = 0.f;
    int e = beg;
    for (; e + 8 <= end; e += 8) {
        uint2 w0 = T2[(size_t)csr[e + 0] * 16 + t];
        uint2 w1 = T2[(size_t)csr[e + 1] * 16 + t];
        uint2 w2 = T2[(size_t)csr[e + 2] * 16 + t];
        uint2 w3 = T2[(size_t)csr[e + 3] * 16 + t];
        uint2 w4 = T2[(size_t)csr[e + 4] * 16 + t];
        uint2 w5 = T2[(size_t)csr[e + 5] * 16 + t];
        uint2 w6 = T2[(size_t)csr[e + 6] * 16 + t];
        uint2 w7 = T2[(size_t)csr[e + 7] * 16 + t];
        f32x2 p;
        p = fp8lo(w0.x); s0 += p[0]; s1 += p[1];
        p = fp8hi(w0.x); s2 += p[0]; s3 += p[1];
        p = fp8lo(w0.y); s4 += p[0]; s5 += p[1];
        p = fp8hi(w0.y); s6 += p[0]; s7 += p[1];
        p = fp8lo(w1.x); s0 += p[0]; s1 += p[1];
        p = fp8hi(w1.x); s2 += p[0]; s3 += p[1];
        p = fp8lo(w1.y); s4 += p[0]; s5 += p[1];
        p = fp8hi(w1.y); s6 += p[0]; s7 += p[1];
        p = fp8lo(w2.x); s0 += p[0]; s1 += p[1];
        p = fp8hi(w2.x); s2 += p[0]; s3 += p[1];
        p = fp8lo(w2.y); s4 += p[0]; s5 += p[1];
        p = fp8hi(w2.y); s6 += p[0]; s7 += p[1];
        p = fp8lo(w3.x); s0 += p[0]; s1 += p[1];
        p = fp8hi(w3.x); s2 += p[0]; s3 += p[1];
        p = fp8lo(w3.y); s4 += p[0]; s5 += p[1];
        p = fp8hi(w3.y); s6 += p[0]; s7 += p[1];
        p = fp8lo(w4.x); s0 += p[0]; s1 += p[1];
        p = fp8hi(w4.x); s2 += p[0]; s3 += p[1];
        p = fp8lo(w4.y); s4 += p[0]; s5 += p[1];
        p = fp8hi(w4.y); s6 += p[0]; s7 += p[1];
        p = fp8lo(w5.x); s0 += p[0]; s1 += p[1];
        p = fp8hi(w5.x); s2 += p[0]; s3 += p[1];
        p = fp8lo(w5.y); s4 += p[0]; s5 += p[1];
        p = fp8hi(w5.y); s6 += p[0]; s7 += p[1];
        p = fp8lo(w6.x); s0 += p[0]; s1 += p[1];
        p = fp8hi(w6.x); s2 += p[0]; s3 += p[1];
        p = fp8lo(w6.y); s4 += p[0]; s5 += p[1];
        p = fp8hi(w6.y); s6 += p[0]; s7 += p[1];
        p = fp8lo(w7.x); s0 += p[0]; s1 += p[1];
        p = fp8hi(w7.x); s2 += p[0]; s3 += p[1];
        p = fp8lo(w7.y); s4 += p[0]; s5 += p[1];
        p = fp8hi(w7.y); s6 += p[0]; s7 += p[1];
    }
    for (; e < end; ++e) {
        uint2 w = T2[(size_t)csr[e] * 16 + t];
        f32x2 p;
        p = fp8lo(w.x); s0 += p[0]; s1 += p[1];
        p = fp8hi(w.x); s2 += p[0]; s3 += p[1];
        p = fp8lo(w.y); s4 += p[0]; s5 += p[1];
        p = fp8hi(w.y); s6 += p[0]; s7 += p[1];
    }
    float di = degInv[v];
    uint4 rw = reinterpret_cast<const uint4*>(tR)[(size_t)v * 16 + t];
    float4 A0 = reinterpret_cast<const float4*>(bnA + t * 8)[0];
    float4 A1 = reinterpret_cast<const float4*>(bnA + t * 8)[1];
    float4 B0 = reinterpret_cast<const float4*>(bnB + t * 8)[0];
    float4 B1 = reinterpret_cast<const float4*>(bnB + t * 8)[1];
    float h0 = fmaxf(A0.x * (s0 * di + blo(rw.x)) + B0.x, 0.f);
    float h1 = fmaxf(A0.y * (s1 * di + bhi(rw.x)) + B0.y, 0.f);
    float h2 = fmaxf(A0.z * (s2 * di + blo(rw.y)) + B0.z, 0.f);
    float h3 = fmaxf(A0.w * (s3 * di + bhi(rw.y)) + B0.w, 0.f);
    float h4 = fmaxf(A1.x * (s4 * di + blo(rw.z)) + B1.x, 0.f);
    float h5 = fmaxf(A1.y * (s5 * di + bhi(rw.z)) + B1.y, 0.f);
    float h6 = fmaxf(A1.z * (s6 * di + blo(rw.w)) + B1.z, 0.f);
    float h7 = fmaxf(A1.w * (s7 * di + bhi(rw.w)) + B1.w, 0.f);
    uint4 o;
    o.x = pack2(h0, h1);
    o.y = pack2(h2, h3);
    o.z = pack2(h4, h5);
    o.w = pack2(h6, h7);
    reinterpret_cast<uint4*>(h)[(size_t)v * 16 + t] = o;
}

// ---------------- final: out = log_softmax( mean-agg(tL2 fp8) + tR2 bf16 ) ----------------
// 8 lanes/node, 8 B per lane, x8-deep gathers.
__global__ void agg64_lsm_kernel(const unsigned char* __restrict__ tL2,
                                 const unsigned short* __restrict__ tR2,
                                 const int* __restrict__ rowptr, const int* __restrict__ csr,
                                 const float* __restrict__ degInv,
                                 float* __restrict__ out, int n) {
    int idx = blockIdx.x * blockDim.x + threadIdx.x;
    int v = idx >> 3;
    int t = idx & 7;
    if (v >= n) return;
    int beg = rowptr[v], end = rowptr[v + 1];
    const uint2* T2 = reinterpret_cast<const uint2*>(tL2);
    float s0 = 0.f, s1 = 0.f, s2 = 0.f, s3 = 0.f, s4 = 0.f, s5 = 0.f, s6 = 0.f, s7 = 0.f;
    int e = beg;
    for (; e + 8 <= end; e += 8) {
        uint2 w0 = T2[(size_t)csr[e + 0] * 8 + t];
        uint2 w1 = T2[(size_t)csr[e + 1] * 8 + t];
        uint2 w2 = T2[(size_t)csr[e + 2] * 8 + t];
        uint2 w3 = T2[(size_t)csr[e + 3] * 8 + t];
        uint2 w4 = T2[(size_t)csr[e + 4] * 8 + t];
        uint2 w5 = T2[(size_t)csr[e + 5] * 8 + t];
        uint2 w6 = T2[(size_t)csr[e + 6] * 8 + t];
        uint2 w7 = T2[(size_t)csr[e + 7] * 8 + t];
        f32x2 p;
        p = fp8lo(w0.x); s0 += p[0]; s1 += p[1];
        p = fp8hi(w0.x); s2 += p[0]; s3 += p[1];
        p = fp8lo(w0.y); s4 += p[0]; s5 += p[1];
        p = fp8hi(w0.y); s6 += p[0]; s7 += p[1];
        p = fp8lo(w1.x); s0 += p[0]; s1 += p[1];
        p = fp8hi(w1.x); s2 += p[0]; s3 += p[1];
        p = fp8lo(w1.y); s4 += p[0]; s5 += p[1];
        p = fp8hi(w1.y); s6 += p[0]; s7 += p[1];
        p = fp8lo(w2.x); s0 += p[0]; s1 += p[1];
        p = fp8hi(w2.x); s2 += p[0]; s3 += p[1];
        p = fp8lo(w2.y); s4 += p[0]; s5 += p[1];
        p = fp8hi(w2.y); s6 += p[0]; s7 += p[1];
        p = fp8lo(w3.x); s0 += p[0]; s1 += p[1];
        p = fp8hi(w3.x); s2 += p[0]; s3 += p[1];
        p = fp8lo(w3.y); s4 += p[0]; s5 += p[1];
        p = fp8hi(w3.y); s6 += p[0]; s7 += p[1];
        p = fp8lo(w4.x); s0 += p[0]; s1 += p[1];
        p = fp8hi(w4.x); s2 += p[0]; s3 += p[1];
        p = fp8lo(w4.y); s4 += p[0]; s5 += p[1];
        p = fp8hi(w4.y); s6 += p[0]; s7 += p[1];
        p = fp8lo(w5.x); s0 += p[0]; s1 += p[1];
        p = fp8hi(w5.x); s2 += p[0]; s3 += p[1];
        p = fp8lo(w5.y); s4 += p[0]; s5 += p[1];
        p = fp8hi(w5.y); s6 += p[0]; s7 += p[1];
        p = fp8lo(w6.x); s0 += p[0]; s1 += p[1];
        p = fp8hi(w6.x); s2 += p[0]; s3 += p[1];
        p = fp8lo(w6.y); s4 += p[0]; s5 += p[1];
        p = fp8hi(w6.y); s6 += p[0]; s7 += p[1];
        p = fp8lo(w7.x); s0 += p[0]; s1 += p[1];
        p = fp8hi(w7.x); s2 += p[0]; s3 += p[1];
        p = fp8lo(w7.y); s4 += p[0]; s5 += p[1];
        p = fp8hi(w7.y); s6 += p[0]; s7 += p[1];
    }
    for (; e < end; ++e) {
        uint2 w = T2[(size_t)csr[e] * 8 + t];
        f32x2 p;
        p = fp8lo(w.x); s0 += p[0]; s1 += p[1];
        p = fp8hi(w.x); s2 += p[0]; s3 += p[1];
        p = fp8lo(w.y); s4 += p[0]; s5 += p[1];
        p = fp8hi(w.y); s6 += p[0]; s7 += p[1];
    }
    float di = degInv[v];
    uint4 rw = reinterpret_cast<const uint4*>(tR2)[(size_t)v * 8 + t];
    float y0 = s0 * di + blo(rw.x);
    float y1 = s1 * di + bhi(rw.x);
    float y2 = s2 * di + blo(rw.y);
    float y3 = s3 * di + bhi(rw.y);
    float y4 = s4 * di + blo(rw.z);
    float y5 = s5 * di + bhi(rw.z);
    float y6 = s6 * di + blo(rw.w);
    float y7 = s7 * di + bhi(rw.w);

    float mx = fmaxf(fmaxf(fmaxf(y0, y1), fmaxf(y2, y3)),
                     fmaxf(fmaxf(y4, y5), fmaxf(y6, y7)));
#pragma unroll
    for (int o = 1; o < 8; o <<= 1) mx = fmaxf(mx, __shfl_xor(mx, o));
    float s = __expf(y0 - mx) + __expf(y1 - mx) + __expf(y2 - mx) + __expf(y3 - mx)
            + __expf(y4 - mx) + __expf(y5 - mx) + __expf(y6 - mx) + __expf(y7 - mx);
#pragma unroll
    for (int o = 1; o < 8; o <<= 1) s += __shfl_xor(s, o);
    float lse = mx + __logf(s);

    float4 oA, oB;
    oA.x = y0 - lse; oA.y = y1 - lse; oA.z = y2 - lse; oA.w = y3 - lse;
    oB.x = y4 - lse; oB.y = y5 - lse; oB.z = y6 - lse; oB.w = y7 - lse;
    float4* O4 = reinterpret_cast<float4*>(out + (size_t)v * 64 + t * 8);
    O4[0] = oA;
    O4[1] = oB;
}

// ---------------- launch ----------------

extern "C" void kernel_launch(void* const* d_in, const int* in_sizes, int n_in,
                              void* d_out, int out_size, void* d_ws, size_t ws_size,
                              hipStream_t stream) {
    const float* x   = (const float*)d_in[0];
    const int*   ei  = (const int*)d_in[1];
    const float* Wl0 = (const float*)d_in[2];
    const float* bl0 = (const float*)d_in[3];
    const float* Wr0 = (const float*)d_in[4];
    const float* g0  = (const float*)d_in[5];
    const float* b0  = (const float*)d_in[6];
    const float* m0  = (const float*)d_in[7];
    const float* v0  = (const float*)d_in[8];
    const float* Wl1 = (const float*)d_in[9];
    const float* bl1 = (const float*)d_in[10];
    const float* Wr1 = (const float*)d_in[11];
    const float* g1  = (const float*)d_in[12];
    const float* b1  = (const float*)d_in[13];
    const float* m1  = (const float*)d_in[14];
    const float* v1  = (const float*)d_in[15];
    const float* Wl2 = (const float*)d_in[16];
    const float* bl2 = (const float*)d_in[17];
    const float* Wr2 = (const float*)d_in[18];
    float* out = (float*)d_out;

    const int N = in_sizes[0] / 128;
    const int E = in_sizes[1] / 2;
    const int B = (N + NPB - 1) >> NPB_LOG;
    const int* src = ei;
    const int* dst = ei + E;

    char* ws = (char*)d_ws;
    size_t off = 0;
    auto alloc = [&](size_t bytes) -> void* {
        void* p = ws + off;
        off += (bytes + 255) & ~(size_t)255;
        return p;
    };
    int*   bcnt    = (int*)alloc(256 * 4);
    int*   bstart  = (int*)alloc(257 * 4);
    int*   cursorB = (int*)alloc(256 * 4);
    int*   rowptr  = (int*)alloc((size_t)(N + 1) * 4);
    float* degInv  = (float*)alloc((size_t)N * 4);
    int*   csr     = (int*)alloc((size_t)E * 4);
    unsigned* ebuf = (unsigned*)alloc((size_t)E * 4);
    unsigned short* hA  = (unsigned short*)alloc((size_t)N * 128 * 2);   // bf16 [N][128]
    unsigned short* hB  = (unsigned short*)alloc((size_t)N * 128 * 2);   // bf16 [N][128]
    unsigned char*  tL  = (unsigned char*)alloc((size_t)N * 128);       // fp8 [N][128]
    unsigned short* tR  = (unsigned short*)alloc((size_t)N * 128 * 2);  // bf16 [N][128]
    unsigned short* Wsw0 = (unsigned short*)alloc(4 * 16 * 64 * 8 * 2);
    unsigned short* Wsw1 = (unsigned short*)alloc(4 * 16 * 64 * 8 * 2);
    unsigned short* Wsw2 = (unsigned short*)alloc(4 * 8 * 64 * 8 * 2);
    float* bnA0 = (float*)alloc(128 * 4);
    float* bnB0 = (float*)alloc(128 * 4);
    float* bnA1 = (float*)alloc(128 * 4);
    float* bnB1 = (float*)alloc(128 * 4);
    unsigned char*  tL2 = tL;   // fp8  [N][64] overlays tL (lifetimes disjoint)
    unsigned short* tR2 = tR;   // bf16 [N][64] overlays tR

    hipMemsetAsync(bcnt, 0, 256 * 4, stream);

    // CSR build + prep
    bucket_hist_kernel<<<512, 256, 0, stream>>>(dst, bcnt, E, B);
    bucket_scan_kernel<<<1, 256, 0, stream>>>(bcnt, bstart, cursorB, B, E);
    partition_kernel<<<(E + 4095) / 4096, 256, 0, stream>>>(src, dst, cursorB, ebuf, E, B);
    build_csr_kernel<<<B, 256, 0, stream>>>(ebuf, bstart, rowptr, degInv, csr, N, B);
    prep_kernel<<<41, 256, 0, stream>>>(Wl0, Wr0, Wl1, Wr1, Wl2, Wr2,
                                        g0, b0, m0, v0, g1, b1, m1, v1,
                                        Wsw0, Wsw1, Wsw2, bnA0, bnB0, bnA1, bnB1);

    int gemmGrid = (N + 63) / 64;
    int aggGrid = (int)(((size_t)N * 16 + 255) / 256);
    int lsmGrid = (int)(((size_t)N * 8 + 255) / 256);

    // layer 0: tL = x@Wl0 (fp8), tR = x@Wr0 + bl0 (bf16); h = ReLU(BN(agg(tL) + tR))
    gemmT_kernel<128, true><<<gemmGrid, 256, 0, stream>>>(x, Wsw0, bl0, tL, tR, N);
    aggbn_kernel<<<aggGrid, 256, 0, stream>>>(tL, tR, bnA0, bnB0, rowptr, csr, degInv, hA, N);
    // layer 1
    gemmT_kernel<128, false><<<gemmGrid, 256, 0, stream>>>(hA, Wsw1, bl1, tL, tR, N);
    aggbn_kernel<<<aggGrid, 256, 0, stream>>>(tL, tR, bnA1, bnB1, rowptr, csr, degInv, hB, N);
    // layer 2: tL2 = h@Wl2 (fp8), tR2 = h@Wr2 + bl2 (bf16); out = lsm(agg(tL2) + tR2)
    gemmT_kernel<64, false><<<gemmGrid, 256, 0, stream>>>(hB, Wsw2, bl2, tL2, tR2, N);
    agg64_lsm_kernel<<<lsmGrid, 256, 0, stream>>>(tL2, tR2, rowptr, csr, degInv, out, N);
}